// Round 10
// baseline (3586.099 us; speedup 1.0000x reference)
//
#include <hip/hip_runtime.h>
#include <hip/hip_bf16.h>
#include <cstdint>
#include <cstddef>

// Problem constants: L=256, B=16, I=2048, H=2048, S=R=T=32
#define L_DIM 256
#define B_DIM 16
#define I_DIM 2048
#define H_DIM 2048
#define G4    8192
#define MROWS 4096
#define NWG   256

typedef __hip_bfloat16 bf16;
typedef __bf16 bf16x8_t __attribute__((ext_vector_type(8)));
typedef _Float16 f16x8_t __attribute__((ext_vector_type(8)));
typedef float f32x4_t   __attribute__((ext_vector_type(4)));

__device__ __forceinline__ bf16 f2b(float f) { return __float2bfloat16(f); }

__device__ __forceinline__ void gl_lds16(const void* g, void* l) {
  __builtin_amdgcn_global_load_lds(
      (const __attribute__((address_space(1))) unsigned int*)g,
      (__attribute__((address_space(3))) unsigned int*)l, 16, 0, 0);
}

__device__ __forceinline__ float sigmoidf_(float x) { return 1.f / (1.f + expf(-x)); }

// Coherent (IC-through) access helpers — same hardware path the working
// flag protocol uses (sc1 store -> IC, sc1 load <- IC), widened to data.
__device__ __forceinline__ f16x8_t load_f16x8_sc(const _Float16* p) {
  f16x8_t r;
  asm volatile("global_load_dwordx4 %0, %1, off sc0 sc1" : "=v"(r) : "v"(p));
  return r;
}
__device__ __forceinline__ void store_short_sc(void* p, unsigned int v) {
  asm volatile("global_store_short %0, %1, off sc0 sc1" :: "v"(p), "v"(v) : "memory");
}

// ---------------------------------------------------------------------------
// K0: prep — fp16 casts (LSTM path), bf16 hi/lo (FWM weights), h0 fp16
// ---------------------------------------------------------------------------
__global__ void prep_kernel(const float* __restrict__ Wih, const float* __restrict__ Whh,
                            const float* __restrict__ inp, const float* __restrict__ Www,
                            const float* __restrict__ Wwb, const float* __restrict__ Wrw,
                            const float* __restrict__ h0,
                            _Float16* __restrict__ Wih_f, _Float16* __restrict__ Whh_f,
                            _Float16* __restrict__ inp_f,
                            bf16* __restrict__ Wq_hi, bf16* __restrict__ Wq_lo,
                            bf16* __restrict__ Wr_hi, bf16* __restrict__ Wr_lo,
                            float* __restrict__ wbpad,
                            _Float16* __restrict__ Xh0)
{
  size_t idx0 = (size_t)blockIdx.x * blockDim.x + threadIdx.x;
  size_t stride = (size_t)gridDim.x * blockDim.x;
  for (size_t i = idx0; i < 16777216ull; i += stride) {
    Wih_f[i] = (_Float16)Wih[i];
    Whh_f[i] = (_Float16)Whh[i];
  }
  for (size_t i = idx0; i < 8388608ull; i += stride) inp_f[i] = (_Float16)inp[i];
  for (size_t i = idx0; i < 262144ull; i += stride) {
    size_t r = i >> 11;
    float q = (r < 97) ? Www[i] : 0.f;
    bf16 qh = f2b(q);
    Wq_hi[i] = qh;
    Wq_lo[i] = f2b(q - (float)qh);
    float rr = Wrw[i];
    bf16 rh = f2b(rr);
    Wr_hi[i] = rh;
    Wr_lo[i] = f2b(rr - (float)rh);
  }
  for (size_t i = idx0; i < 128ull; i += stride) wbpad[i] = (i < 97) ? Wwb[i] : 0.f;
  for (size_t i = idx0; i < 32768ull; i += stride) Xh0[i] = (_Float16)h0[i];
}

// ---------------------------------------------------------------------------
// K1: fp16 NT GEMM  C(M,N) = A(M,K) * B(N,K)^T + bias[col]  (fp32 out)
// ---------------------------------------------------------------------------
__global__ __launch_bounds__(256) void gemm_f16(const _Float16* __restrict__ A,
                                                const _Float16* __restrict__ B,
                                                const float* __restrict__ bih,
                                                const float* __restrict__ bhh,
                                                float* __restrict__ C,
                                                int M, int N, int K)
{
  __shared__ __align__(16) _Float16 As[128 * 32];
  __shared__ __align__(16) _Float16 Bs[128 * 32];
  const int tid  = threadIdx.x;
  const int lane = tid & 63;
  const int w    = tid >> 6;
  const int wm   = w >> 1, wn = w & 1;
  const int m0   = blockIdx.x * 128, n0 = blockIdx.y * 128;

  f32x4_t acc[4][4];
#pragma unroll
  for (int m = 0; m < 4; ++m)
#pragma unroll
    for (int n = 0; n < 4; ++n) acc[m][n] = (f32x4_t){0.f, 0.f, 0.f, 0.f};

  for (int k0 = 0; k0 < K; k0 += 32) {
#pragma unroll
    for (int r = 0; r < 2; ++r) {
      const int base = w * 2048 + r * 1024;
      const int off  = base + lane * 16;
      const int e    = off >> 1;
      const int row  = e >> 5;
      const int col  = e & 31;
      gl_lds16(A + (size_t)(m0 + row) * K + (k0 + col), (char*)As + base);
      gl_lds16(B + (size_t)(n0 + row) * K + (k0 + col), (char*)Bs + base);
    }
    __syncthreads();

    f16x8_t af[4], bfr[4];
    const int kb = (lane >> 4) * 16;
#pragma unroll
    for (int m = 0; m < 4; ++m)
      af[m] = *reinterpret_cast<const f16x8_t*>((const char*)As + (wm * 64 + m * 16 + (lane & 15)) * 64 + kb);
#pragma unroll
    for (int n = 0; n < 4; ++n)
      bfr[n] = *reinterpret_cast<const f16x8_t*>((const char*)Bs + (wn * 64 + n * 16 + (lane & 15)) * 64 + kb);
#pragma unroll
    for (int m = 0; m < 4; ++m)
#pragma unroll
      for (int n = 0; n < 4; ++n)
        acc[m][n] = __builtin_amdgcn_mfma_f32_16x16x32_f16(af[m], bfr[n], acc[m][n], 0, 0, 0);
    __syncthreads();
  }

#pragma unroll
  for (int m = 0; m < 4; ++m) {
#pragma unroll
    for (int n = 0; n < 4; ++n) {
      const int col = n0 + wn * 64 + n * 16 + (lane & 15);
      const float bv = bih[col] + bhh[col];
#pragma unroll
      for (int r = 0; r < 4; ++r) {
        const int row = m0 + wm * 64 + m * 16 + (lane >> 4) * 4 + r;
        C[(size_t)row * N + col] = acc[m][n][r] + bv;
      }
    }
  }
}

// ---------------------------------------------------------------------------
// K2: persistent LSTM. 256 WGs x 512 thr (8 waves), cooperative.
// W_hh fp16 fragments register-resident; fence-free IC h-exchange (round 8).
// ---------------------------------------------------------------------------
__global__ __launch_bounds__(512, 2) void lstm_persist(
    const _Float16* __restrict__ Whh,
    const float* __restrict__ Gin,
    const float* __restrict__ bih, const float* __restrict__ bhh,
    const float* __restrict__ c0,
    _Float16* __restrict__ Xh,          // 257 slots (16,2048) fp16
    bf16* __restrict__ XhHi, bf16* __restrict__ XhLo,  // 256 slots
    int* flags)                          // NWG x 16 ints (64B stride)
{
  const int tid  = threadIdx.x;
  const int lane = tid & 63;
  const int wv   = tid >> 6;          // 0..7
  const int wg   = blockIdx.x;        // 0..255
  const int j0   = wg * 8;
  const int kw   = wv * 256;

  __shared__ float part[8][2][16][17];   // padded: conflict-free reduce

  // ---- register-resident W_hh fragments (B-operand layout) ----
  f16x8_t whh[2][8];
  {
    const int nn  = lane & 15;
    const int kfo = (lane >> 4) * 8;
#pragma unroll
    for (int nt = 0; nt < 2; ++nt) {
      const int n = nt * 16 + nn;
      const int gate = n >> 3, jj = n & 7;
      const size_t grow = (size_t)(gate * H_DIM + j0 + jj) * 2048;
#pragma unroll
      for (int ks = 0; ks < 8; ++ks)
        whh[nt][ks] = *reinterpret_cast<const f16x8_t*>(Whh + grow + kw + ks * 32 + kfo);
    }
  }

  // ---- per-thread cell state + bias (threads 0..127) ----
  float c_reg = 0.f, cbr0 = 0.f, cbr1 = 0.f, cbr2 = 0.f, cbr3 = 0.f;
  if (tid < 128) {
    const int bb = tid & 15, jj = tid >> 4;
    const int j = j0 + jj;
    c_reg = c0[bb * H_DIM + j];
    cbr0 = bih[0 * H_DIM + j] + bhh[0 * H_DIM + j];
    cbr1 = bih[1 * H_DIM + j] + bhh[1 * H_DIM + j];
    cbr2 = bih[2 * H_DIM + j] + bhh[2 * H_DIM + j];
    cbr3 = bih[3 * H_DIM + j] + bhh[3 * H_DIM + j];
  }

  const size_t arow = (size_t)(lane & 15) * 2048 + kw + (lane >> 4) * 8;

  for (int t = 0; t < L_DIM; ++t) {
    // Gin for this step (plain cached loads; written by a prior kernel)
    float gin0 = 0.f, gin1 = 0.f, gin2 = 0.f, gin3 = 0.f;
    if (tid < 128) {
      const int bb = tid & 15, jj = tid >> 4;
      const size_t gb = ((size_t)t * 16 + bb) * G4 + j0 + jj;
      gin0 = Gin[gb + 0 * H_DIM];
      gin1 = Gin[gb + 1 * H_DIM];
      gin2 = Gin[gb + 2 * H_DIM];
      gin3 = Gin[gb + 3 * H_DIM];
    }

    // h fragments from Xh slot t — coherent IC reads (bypass L1/L2)
    const size_t hoff = (size_t)t * 32768 + arow;
    f16x8_t hf[8];
#pragma unroll
    for (int ks = 0; ks < 8; ++ks)
      hf[ks] = load_f16x8_sc(Xh + hoff + ks * 32);
    asm volatile("s_waitcnt vmcnt(0)" ::: "memory");
    __builtin_amdgcn_sched_barrier(0);   // rule #18: keep MFMAs below the wait

    f32x4_t acc0 = {0.f, 0.f, 0.f, 0.f}, acc1 = {0.f, 0.f, 0.f, 0.f};
#pragma unroll
    for (int ks = 0; ks < 8; ++ks) {
      acc0 = __builtin_amdgcn_mfma_f32_16x16x32_f16(hf[ks], whh[0][ks], acc0, 0, 0, 0);
      acc1 = __builtin_amdgcn_mfma_f32_16x16x32_f16(hf[ks], whh[1][ks], acc1, 0, 0, 0);
    }
#pragma unroll
    for (int r = 0; r < 4; ++r) {
      part[wv][0][(lane >> 4) * 4 + r][lane & 15] = acc0[r];
      part[wv][1][(lane >> 4) * 4 + r][lane & 15] = acc1[r];
    }
    __syncthreads();

    if (tid < 128) {
      const int bb = tid & 15, jj = tid >> 4;
      float g[4] = {gin0, gin1, gin2, gin3};
      const float cb4[4] = {cbr0, cbr1, cbr2, cbr3};
#pragma unroll
      for (int gate = 0; gate < 4; ++gate) {
        const int n = gate * 8 + jj;
        const int ntile = n >> 4, nc = n & 15;
        float s = 0.f;
#pragma unroll
        for (int v = 0; v < 8; ++v) s += part[v][ntile][bb][nc];
        g[gate] += s + cb4[gate];
      }
      const float i_ = sigmoidf_(g[0]);
      const float f_ = sigmoidf_(g[1]);
      const float g_ = tanhf(g[2]);
      const float o_ = sigmoidf_(g[3]);
      c_reg = f_ * c_reg + i_ * g_;
      const float h = o_ * tanhf(c_reg);
      const int bj = bb * 2048 + j0 + jj;
      // write-through (IC) stores: fp16 for recurrence, bf16 hi/lo for FWM
      const _Float16 hF = (_Float16)h;
      const bf16 hhv = f2b(h);
      const bf16 hlv = f2b(h - (float)hhv);
      const size_t xi = ((size_t)t * 16 + bb) * 2048 + j0 + jj;
      store_short_sc(Xh + (size_t)(t + 1) * 32768 + bj,
                     (unsigned int)__builtin_bit_cast(unsigned short, hF));
      store_short_sc(XhHi + xi,
                     (unsigned int)__builtin_bit_cast(unsigned short, hhv));
      store_short_sc(XhLo + xi,
                     (unsigned int)__builtin_bit_cast(unsigned short, hlv));
    }
    // drain write-through stores to IC before publishing arrival
    asm volatile("s_waitcnt vmcnt(0)" ::: "memory");
    __syncthreads();

    if (t < L_DIM - 1) {
      const int target = t + 1;
      if (tid == 0)
        __hip_atomic_store(&flags[wg << 4], target, __ATOMIC_RELAXED,
                           __HIP_MEMORY_SCOPE_AGENT);
      if (tid < NWG) {
        while (__hip_atomic_load(&flags[tid << 4], __ATOMIC_RELAXED,
                                 __HIP_MEMORY_SCOPE_AGENT) < target)
          __builtin_amdgcn_s_sleep(1);
      }
      __syncthreads();
    }
  }
}

// ---------------------------------------------------------------------------
// K3: split-bf16 (hi+lo) NT GEMM — ~fp32 via 3 products (FWM projections).
// MODE 1: C = acc + bias ; MODE 2: C = tanh(acc + bias)
// ---------------------------------------------------------------------------
template <int MODE>
__global__ __launch_bounds__(256) void gemm_nt3(const bf16* __restrict__ A_hi,
                                                const bf16* __restrict__ A_lo,
                                                const bf16* __restrict__ B_hi,
                                                const bf16* __restrict__ B_lo,
                                                const float* __restrict__ bias,
                                                float* __restrict__ C,
                                                int M, int N, int K)
{
  __shared__ __align__(16) bf16 As[2][128 * 32];
  __shared__ __align__(16) bf16 Bs[2][128 * 32];
  const int tid  = threadIdx.x;
  const int lane = tid & 63;
  const int w    = tid >> 6;
  const int wm   = w >> 1, wn = w & 1;
  const int m0   = blockIdx.x * 128, n0 = blockIdx.y * 128;

  f32x4_t acc[4][4];
#pragma unroll
  for (int m = 0; m < 4; ++m)
#pragma unroll
    for (int n = 0; n < 4; ++n) acc[m][n] = (f32x4_t){0.f, 0.f, 0.f, 0.f};

  for (int k0 = 0; k0 < K; k0 += 32) {
#pragma unroll
    for (int r = 0; r < 2; ++r) {
      const int base = w * 2048 + r * 1024;
      const int off  = base + lane * 16;
      const int e    = off >> 1;
      const int row  = e >> 5;
      const int col  = e & 31;
      const size_t gA = (size_t)(m0 + row) * K + (k0 + col);
      const size_t gB = (size_t)(n0 + row) * K + (k0 + col);
      gl_lds16(A_hi + gA, (char*)As[0] + base);
      gl_lds16(A_lo + gA, (char*)As[1] + base);
      gl_lds16(B_hi + gB, (char*)Bs[0] + base);
      gl_lds16(B_lo + gB, (char*)Bs[1] + base);
    }
    __syncthreads();

    bf16x8_t afh[4], afl[4], bfh[4], bfl[4];
    const int kb = (lane >> 4) * 16;
#pragma unroll
    for (int m = 0; m < 4; ++m) {
      const int ro = (wm * 64 + m * 16 + (lane & 15)) * 64 + kb;
      afh[m] = *reinterpret_cast<const bf16x8_t*>((const char*)As[0] + ro);
      afl[m] = *reinterpret_cast<const bf16x8_t*>((const char*)As[1] + ro);
    }
#pragma unroll
    for (int n = 0; n < 4; ++n) {
      const int ro = (wn * 64 + n * 16 + (lane & 15)) * 64 + kb;
      bfh[n] = *reinterpret_cast<const bf16x8_t*>((const char*)Bs[0] + ro);
      bfl[n] = *reinterpret_cast<const bf16x8_t*>((const char*)Bs[1] + ro);
    }
#pragma unroll
    for (int m = 0; m < 4; ++m)
#pragma unroll
      for (int n = 0; n < 4; ++n) {
        acc[m][n] = __builtin_amdgcn_mfma_f32_16x16x32_bf16(afh[m], bfh[n], acc[m][n], 0, 0, 0);
        acc[m][n] = __builtin_amdgcn_mfma_f32_16x16x32_bf16(afh[m], bfl[n], acc[m][n], 0, 0, 0);
        acc[m][n] = __builtin_amdgcn_mfma_f32_16x16x32_bf16(afl[m], bfh[n], acc[m][n], 0, 0, 0);
      }
    __syncthreads();
  }

#pragma unroll
  for (int m = 0; m < 4; ++m) {
#pragma unroll
    for (int n = 0; n < 4; ++n) {
      const int col = n0 + wn * 64 + n * 16 + (lane & 15);
      const float bv = bias[col];
#pragma unroll
      for (int r = 0; r < 4; ++r) {
        const int row = m0 + wm * 64 + m * 16 + (lane >> 4) * 4 + r;
        float v = acc[m][n][r] + bv;
        if (MODE == 2) v = tanhf(v);
        C[(size_t)row * N + col] = v;
      }
    }
  }
}

// ---------------------------------------------------------------------------
// K4: FWM scan v3. 16 WGs x 256 thr (4 waves). Wave wv owns t-cols
// [8wv,8wv+8); lane owns k in [16*lane,+16); F[16][8] in registers.
// No LDS staging (per-lane redundant tanh from L2/IC rows); 3 barriers/step;
// q-chain on wave 0 with 2-lanes-per-t split + shfl broadcast, overlapping
// waves 1-3's next-step staging. Incremental norm (round-9, validated).
// ---------------------------------------------------------------------------
__global__ __launch_bounds__(256, 1) void fwm_scan(const float* __restrict__ Wall,   // (4096,128)
                                                   const float* __restrict__ RVall,  // (4096,128)
                                                   const float* __restrict__ F0,     // (16,1024,32)
                                                   float* __restrict__ QS)           // (4096,32)
{
  const int b    = blockIdx.x;
  const int tid  = threadIdx.x;
  const int lane = tid & 63;
  const int wv   = tid >> 6;          // 0..3
  const int si    = lane >> 1;        // s-index for this lane's k-range
  const int rbase = 16 * (lane & 1);  // r-index base
  const int tq    = lane & 31;        // q-column (wave 0, dual-half)

  __shared__ float s_v[32], s_u[32];
  __shared__ float s_inv;
  __shared__ float s_red[4];
  __shared__ float s_G[3][32][33];    // padded: conflict-free

  float F[16][8];
#pragma unroll
  for (int i = 0; i < 16; ++i)
#pragma unroll
    for (int j = 0; j < 8; ++j)
      F[i][j] = F0[((size_t)b * 1024 + (16 * lane + i)) * 32 + 8 * wv + j];

  // initial ||F||^2 (one-time full reduce); N maintained by wave 0
  float N = 0.f;
  {
    float loc = 0.f;
#pragma unroll
    for (int i = 0; i < 16; ++i)
#pragma unroll
      for (int j = 0; j < 8; ++j) loc += F[i][j] * F[i][j];
#pragma unroll
    for (int m = 1; m < 64; m <<= 1) loc += __shfl_xor(loc, m);
    if (lane == 0) s_red[wv] = loc;
    __syncthreads();
    N = s_red[0] + s_red[1] + s_red[2] + s_red[3];
    __syncthreads();
  }

  for (int t = 0; t < 256; ++t) {
    const float* wrow  = Wall  + (size_t)(t * 16 + b) * 128;
    const float* rvrow = RVall + (size_t)(t * 16 + b) * 128;

    // issue all loads for this step up front (consumed progressively)
    const float w_s = wrow[si];
    f32x4_t w_r[4];
#pragma unroll
    for (int ks = 0; ks < 4; ++ks)
      w_r[ks] = *reinterpret_cast<const f32x4_t*>(wrow + 32 + rbase + 4 * ks);
    f32x4_t rv_j[3][4];
#pragma unroll
    for (int jit = 0; jit < 3; ++jit)
#pragma unroll
      for (int ks = 0; ks < 4; ++ks)
        rv_j[jit][ks] = *reinterpret_cast<const f32x4_t*>(rvrow + 32 + 32 * jit + rbase + 4 * ks);
    float w0_s = 0.f, w0_r = 0.f, w0_tv = 0.f, w0_bb = 0.f, rv_q = 0.f;
    if (wv == 0) {
      w0_s  = wrow[tq];
      w0_r  = wrow[32 + tq];
      w0_tv = wrow[64 + tq];
      w0_bb = wrow[96];
      rv_q  = rvrow[tq];
    }

    const float sv = tanhf(w_s);
    float sr[16];
#pragma unroll
    for (int ks = 0; ks < 4; ++ks)
#pragma unroll
      for (int e = 0; e < 4; ++e)
        sr[4 * ks + e] = sv * tanhf(w_r[ks][e]);

    // v_t = sum_k sr[k] F[k,t]  (8 wave-local t-columns)
    float vv[8];
#pragma unroll
    for (int j = 0; j < 8; ++j) {
      float pp = 0.f;
#pragma unroll
      for (int i = 0; i < 16; ++i) pp += sr[i] * F[i][j];
#pragma unroll
      for (int m = 1; m < 64; m <<= 1) pp += __shfl_xor(pp, m);
      vv[j] = pp;
    }
    if (lane == 0) {
#pragma unroll
      for (int j = 0; j < 8; ++j) s_v[8 * wv + j] = vv[j];
    }
    __syncthreads();                  // 1

    // wave 0: u, incremental norm, inv  (values replicated across halves)
    if (wv == 0) {
      const float vt  = s_v[tq];
      const float tvt = tanhf(w0_tv);
      const float bbv = sigmoidf_(w0_bb + 1.f);
      const float ut  = bbv * (tvt - vt);
      s_u[tq] = ut;                   // duplicate write, same value — benign
      const float sl = tanhf(w0_s);
      const float rl = tanhf(w0_r);
      float uv = ut * vt, uu = ut * ut, ss = sl * sl, rr = rl * rl;
#pragma unroll
      for (int m = 1; m < 32; m <<= 1) {
        uv += __shfl_xor(uv, m);
        uu += __shfl_xor(uu, m);
        ss += __shfl_xor(ss, m);
        rr += __shfl_xor(rr, m);
      }
      const float Np  = N + 2.f * uv + ss * rr * uu;
      const float n_  = sqrtf(Np);
      const float inv = 1.f / (fmaxf(n_ - 1.f, 0.f) + 1.f);
      N = Np * inv * inv;
      if (lane == 0) s_inv = inv;
    }
    __syncthreads();                  // 2

    // F update + scale, then G matrices (G_jit[i,t] = sum_j rj[j] F[32i+j,t])
    const float inv = s_inv;
    float uw[8];
#pragma unroll
    for (int j = 0; j < 8; ++j) uw[j] = s_u[8 * wv + j];
#pragma unroll
    for (int i = 0; i < 16; ++i)
#pragma unroll
      for (int j = 0; j < 8; ++j)
        F[i][j] = (F[i][j] + sr[i] * uw[j]) * inv;

#pragma unroll
    for (int jit = 0; jit < 3; ++jit) {
#pragma unroll
      for (int j = 0; j < 8; ++j) {
        float g = 0.f;
#pragma unroll
        for (int i = 0; i < 16; ++i)
          g += rv_j[jit][i >> 2][i & 3] * F[i][j];
        g += __shfl_xor(g, 1);        // combine the two j-halves of row i
        if ((lane & 1) == 0) s_G[jit][lane >> 1][8 * wv + j] = g;
      }
    }
    __syncthreads();                  // 3

    // wave 0: q-chain (3 x 32x32 matvec + LN), 2 lanes per t-column;
    // overlaps waves 1-3 proceeding to next step's staging (they stop at
    // barrier 1 of step t+1; all s_* hazards barrier-protected — see notes).
    if (wv == 0) {
      float q = rv_q;                 // q_t at lanes t and t+32
      const int ihalf = (lane >> 5) * 16;
#pragma unroll 1
      for (int jit = 0; jit < 3; ++jit) {
        float c = 0.f;
#pragma unroll
        for (int i = 0; i < 16; ++i) {
          const float qi = __shfl(q, ihalf + i);   // lanes 0..31 hold q_t
          c += qi * s_G[jit][ihalf + i][tq];
        }
        c += __shfl_xor(c, 32);       // both halves now hold full c_t
        float mval = c;
#pragma unroll
        for (int m = 1; m < 32; m <<= 1) mval += __shfl_xor(mval, m);
        mval *= (1.f / 32.f);
        const float dl = c - mval;
        float var = dl * dl;
#pragma unroll
        for (int m = 1; m < 32; m <<= 1) var += __shfl_xor(var, m);
        var *= (1.f / 32.f);
        q = dl * rsqrtf(var + 1e-5f);
      }
      if (lane < 32) QS[(size_t)(t * 16 + b) * 32 + lane] = q;
    }
  }
}

// ---------------------------------------------------------------------------
// K5: out = (XhHi+XhLo) + QS @ Wlin^T + blin
// ---------------------------------------------------------------------------
__global__ __launch_bounds__(256) void out_kernel(const bf16* __restrict__ Xh1Hi,
                                                  const bf16* __restrict__ Xh1Lo,
                                                  const float* __restrict__ QS,
                                                  const float* __restrict__ Wlin,  // (2048,32)
                                                  const float* __restrict__ blin,
                                                  float* __restrict__ out)
{
  __shared__ float qs[32];
  const int row = blockIdx.x;
  if (threadIdx.x < 32) qs[threadIdx.x] = QS[(size_t)row * 32 + threadIdx.x];
  __syncthreads();
  for (int h = threadIdx.x; h < H_DIM; h += 256) {
    const size_t xi = (size_t)row * H_DIM + h;
    float acc = (float)Xh1Hi[xi] + (float)Xh1Lo[xi] + blin[h];
    const float* wr = Wlin + (size_t)h * 32;
#pragma unroll
    for (int t2 = 0; t2 < 32; ++t2) acc += qs[t2] * wr[t2];
    out[xi] = acc;
  }
}

// ---------------------------------------------------------------------------
// Workspace (~237 MB), lifetime-aliased:
//  Whh_f16 33.5 | Wih_f16 33.5 (XhLo aliases after Gin GEMM) |
//  inp_f16 16.8 (XhHi aliases) | Gin 134 (Wall/RVall/QS alias after persist) |
//  Xh_f16 16.9 | Wq/Wr hi/lo 2.1 | flags 16KB | smalls
// ---------------------------------------------------------------------------
extern "C" void kernel_launch(void* const* d_in, const int* in_sizes, int n_in,
                              void* d_out, int out_size, void* d_ws, size_t ws_size,
                              hipStream_t stream)
{
  (void)in_sizes; (void)n_in; (void)out_size; (void)ws_size;
  const float* inp  = (const float*)d_in[0];
  const float* h0   = (const float*)d_in[1];
  const float* c0   = (const float*)d_in[2];
  const float* F0   = (const float*)d_in[3];
  const float* Wih  = (const float*)d_in[4];
  const float* Whh  = (const float*)d_in[5];
  const float* bih  = (const float*)d_in[6];
  const float* bhh  = (const float*)d_in[7];
  const float* Www  = (const float*)d_in[8];
  const float* Wwb  = (const float*)d_in[9];
  const float* Wrw  = (const float*)d_in[10];
  const float* Wrb  = (const float*)d_in[11];
  const float* Wlin = (const float*)d_in[12];
  const float* blin = (const float*)d_in[13];
  float* out = (float*)d_out;

  char* p = (char*)d_ws;
  auto alloc = [&](size_t bytes) {
    char* r = p;
    p += (bytes + 255) & ~(size_t)255;
    return r;
  };
  _Float16* Whh_f = (_Float16*)alloc(16777216ull * 2);   // 33.5 MB
  _Float16* Wih_f = (_Float16*)alloc(16777216ull * 2);   // 33.5 MB
  _Float16* inp_f = (_Float16*)alloc(8388608ull * 2);    // 16.8 MB
  float*    Gin   = (float*)alloc(33554432ull * 4);      // 134 MB (4096x8192)
  _Float16* Xh    = (_Float16*)alloc(257ull * 32768 * 2);// 16.9 MB
  bf16*  Wq_hi  = (bf16*)alloc(262144ull * 2);
  bf16*  Wq_lo  = (bf16*)alloc(262144ull * 2);
  bf16*  Wr_hi  = (bf16*)alloc(262144ull * 2);
  bf16*  Wr_lo  = (bf16*)alloc(262144ull * 2);
  float* wbpad  = (float*)alloc(128ull * 4);
  int*   flags  = (int*)alloc(NWG * 64);                 // 64B line per WG
  // aliases (strictly later lifetimes):
  bf16*  XhHi  = (bf16*)inp_f;          // written by persist after Gin GEMM consumed inp_f
  bf16*  XhLo  = (bf16*)Wih_f;          // written after Wih consumed
  float* Wall  = Gin;                   // 2 MB, written after persist consumed Gin
  float* RVall = Gin + 524288;          // 2 MB
  float* QS    = Gin + 1048576;         // 0.5 MB

  prep_kernel<<<2048, 256, 0, stream>>>(Wih, Whh, inp, Www, Wwb, Wrw, h0,
                                        Wih_f, Whh_f, inp_f,
                                        Wq_hi, Wq_lo, Wr_hi, Wr_lo, wbpad, Xh);

  // Phase A: Gin = x @ W_ih^T + (b_ih + b_hh)   (fp16 inputs, fp32 out)
  gemm_f16<<<dim3(32, 64), 256, 0, stream>>>(inp_f, Wih_f, bih, bhh, Gin,
                                             MROWS, G4, 2048);

  // Phase B: persistent cooperative LSTM (W_hh register-resident, fp16)
  hipMemsetAsync(flags, 0, NWG * 64, stream);
  {
    void* kargs[] = {
      (void*)&Whh_f, (void*)&Gin, (void*)&bih, (void*)&bhh, (void*)&c0,
      (void*)&Xh, (void*)&XhHi, (void*)&XhLo, (void*)&flags
    };
    hipLaunchCooperativeKernel((const void*)lstm_persist, dim3(NWG), dim3(512),
                               kargs, 0, stream);
  }

  // Phase C: FWM projections (~fp32 via split-bf16)
  gemm_nt3<1><<<dim3(32, 1), 256, 0, stream>>>(XhHi, XhLo, Wq_hi, Wq_lo, wbpad,
                                               Wall, MROWS, 128, 2048);
  gemm_nt3<2><<<dim3(32, 1), 256, 0, stream>>>(XhHi, XhLo, Wr_hi, Wr_lo, Wrb,
                                               RVall, MROWS, 128, 2048);

  // Phase D: FWM scan v3 (4 waves, 3 barriers, overlap q-chain)
  fwm_scan<<<16, 256, 0, stream>>>(Wall, RVall, F0, QS);

  // Phase E: out = x + QS @ Wlin^T + blin
  out_kernel<<<4096, 256, 0, stream>>>(XhHi, XhLo, QS, Wlin, blin, out);
}

// Round 11
// 2679.731 us; speedup vs baseline: 1.3382x; 1.3382x over previous
//
#include <hip/hip_runtime.h>
#include <hip/hip_bf16.h>
#include <cstdint>
#include <cstddef>

// Problem constants: L=256, B=16, I=2048, H=2048, S=R=T=32
#define L_DIM 256
#define B_DIM 16
#define I_DIM 2048
#define H_DIM 2048
#define G4    8192
#define MROWS 4096
#define NWG   256

typedef __hip_bfloat16 bf16;
typedef __bf16 bf16x8_t __attribute__((ext_vector_type(8)));
typedef _Float16 f16x8_t __attribute__((ext_vector_type(8)));
typedef float f32x4_t   __attribute__((ext_vector_type(4)));

__device__ __forceinline__ bf16 f2b(float f) { return __float2bfloat16(f); }

__device__ __forceinline__ void gl_lds16(const void* g, void* l) {
  __builtin_amdgcn_global_load_lds(
      (const __attribute__((address_space(1))) unsigned int*)g,
      (__attribute__((address_space(3))) unsigned int*)l, 16, 0, 0);
}

__device__ __forceinline__ float sigmoidf_(float x) { return 1.f / (1.f + expf(-x)); }

// Coherent (IC-through) access helpers — same hardware path the working
// flag protocol uses (sc1 store -> IC, sc1 load <- IC), widened to data.
__device__ __forceinline__ f16x8_t load_f16x8_sc(const _Float16* p) {
  f16x8_t r;
  asm volatile("global_load_dwordx4 %0, %1, off sc0 sc1" : "=v"(r) : "v"(p));
  return r;
}
__device__ __forceinline__ void store_short_sc(void* p, unsigned int v) {
  asm volatile("global_store_short %0, %1, off sc0 sc1" :: "v"(p), "v"(v) : "memory");
}

// ---------------------------------------------------------------------------
// K0: prep — fp16 casts (LSTM path), bf16 hi/lo (FWM weights), h0 fp16
// ---------------------------------------------------------------------------
__global__ void prep_kernel(const float* __restrict__ Wih, const float* __restrict__ Whh,
                            const float* __restrict__ inp, const float* __restrict__ Www,
                            const float* __restrict__ Wwb, const float* __restrict__ Wrw,
                            const float* __restrict__ h0,
                            _Float16* __restrict__ Wih_f, _Float16* __restrict__ Whh_f,
                            _Float16* __restrict__ inp_f,
                            bf16* __restrict__ Wq_hi, bf16* __restrict__ Wq_lo,
                            bf16* __restrict__ Wr_hi, bf16* __restrict__ Wr_lo,
                            float* __restrict__ wbpad,
                            _Float16* __restrict__ Xh0)
{
  size_t idx0 = (size_t)blockIdx.x * blockDim.x + threadIdx.x;
  size_t stride = (size_t)gridDim.x * blockDim.x;
  for (size_t i = idx0; i < 16777216ull; i += stride) {
    Wih_f[i] = (_Float16)Wih[i];
    Whh_f[i] = (_Float16)Whh[i];
  }
  for (size_t i = idx0; i < 8388608ull; i += stride) inp_f[i] = (_Float16)inp[i];
  for (size_t i = idx0; i < 262144ull; i += stride) {
    size_t r = i >> 11;
    float q = (r < 97) ? Www[i] : 0.f;
    bf16 qh = f2b(q);
    Wq_hi[i] = qh;
    Wq_lo[i] = f2b(q - (float)qh);
    float rr = Wrw[i];
    bf16 rh = f2b(rr);
    Wr_hi[i] = rh;
    Wr_lo[i] = f2b(rr - (float)rh);
  }
  for (size_t i = idx0; i < 128ull; i += stride) wbpad[i] = (i < 97) ? Wwb[i] : 0.f;
  for (size_t i = idx0; i < 32768ull; i += stride) Xh0[i] = (_Float16)h0[i];
}

// ---------------------------------------------------------------------------
// K1: fp16 NT GEMM  C(M,N) = A(M,K) * B(N,K)^T + bias[col]  (fp32 out)
// ---------------------------------------------------------------------------
__global__ __launch_bounds__(256) void gemm_f16(const _Float16* __restrict__ A,
                                                const _Float16* __restrict__ B,
                                                const float* __restrict__ bih,
                                                const float* __restrict__ bhh,
                                                float* __restrict__ C,
                                                int M, int N, int K)
{
  __shared__ __align__(16) _Float16 As[128 * 32];
  __shared__ __align__(16) _Float16 Bs[128 * 32];
  const int tid  = threadIdx.x;
  const int lane = tid & 63;
  const int w    = tid >> 6;
  const int wm   = w >> 1, wn = w & 1;
  const int m0   = blockIdx.x * 128, n0 = blockIdx.y * 128;

  f32x4_t acc[4][4];
#pragma unroll
  for (int m = 0; m < 4; ++m)
#pragma unroll
    for (int n = 0; n < 4; ++n) acc[m][n] = (f32x4_t){0.f, 0.f, 0.f, 0.f};

  for (int k0 = 0; k0 < K; k0 += 32) {
#pragma unroll
    for (int r = 0; r < 2; ++r) {
      const int base = w * 2048 + r * 1024;
      const int off  = base + lane * 16;
      const int e    = off >> 1;
      const int row  = e >> 5;
      const int col  = e & 31;
      gl_lds16(A + (size_t)(m0 + row) * K + (k0 + col), (char*)As + base);
      gl_lds16(B + (size_t)(n0 + row) * K + (k0 + col), (char*)Bs + base);
    }
    __syncthreads();

    f16x8_t af[4], bfr[4];
    const int kb = (lane >> 4) * 16;
#pragma unroll
    for (int m = 0; m < 4; ++m)
      af[m] = *reinterpret_cast<const f16x8_t*>((const char*)As + (wm * 64 + m * 16 + (lane & 15)) * 64 + kb);
#pragma unroll
    for (int n = 0; n < 4; ++n)
      bfr[n] = *reinterpret_cast<const f16x8_t*>((const char*)Bs + (wn * 64 + n * 16 + (lane & 15)) * 64 + kb);
#pragma unroll
    for (int m = 0; m < 4; ++m)
#pragma unroll
      for (int n = 0; n < 4; ++n)
        acc[m][n] = __builtin_amdgcn_mfma_f32_16x16x32_f16(af[m], bfr[n], acc[m][n], 0, 0, 0);
    __syncthreads();
  }

#pragma unroll
  for (int m = 0; m < 4; ++m) {
#pragma unroll
    for (int n = 0; n < 4; ++n) {
      const int col = n0 + wn * 64 + n * 16 + (lane & 15);
      const float bv = bih[col] + bhh[col];
#pragma unroll
      for (int r = 0; r < 4; ++r) {
        const int row = m0 + wm * 64 + m * 16 + (lane >> 4) * 4 + r;
        C[(size_t)row * N + col] = acc[m][n][r] + bv;
      }
    }
  }
}

// ---------------------------------------------------------------------------
// K2: persistent LSTM. 256 WGs x 512 thr (8 waves), cooperative.
// W_hh fp16 fragments register-resident; fence-free IC h-exchange (round 8).
// ---------------------------------------------------------------------------
__global__ __launch_bounds__(512, 2) void lstm_persist(
    const _Float16* __restrict__ Whh,
    const float* __restrict__ Gin,
    const float* __restrict__ bih, const float* __restrict__ bhh,
    const float* __restrict__ c0,
    _Float16* __restrict__ Xh,          // 257 slots (16,2048) fp16
    bf16* __restrict__ XhHi, bf16* __restrict__ XhLo,  // 256 slots
    int* flags)                          // NWG x 16 ints (64B stride)
{
  const int tid  = threadIdx.x;
  const int lane = tid & 63;
  const int wv   = tid >> 6;          // 0..7
  const int wg   = blockIdx.x;        // 0..255
  const int j0   = wg * 8;
  const int kw   = wv * 256;

  __shared__ float part[8][2][16][17];   // padded: conflict-free reduce

  // ---- register-resident W_hh fragments (B-operand layout) ----
  f16x8_t whh[2][8];
  {
    const int nn  = lane & 15;
    const int kfo = (lane >> 4) * 8;
#pragma unroll
    for (int nt = 0; nt < 2; ++nt) {
      const int n = nt * 16 + nn;
      const int gate = n >> 3, jj = n & 7;
      const size_t grow = (size_t)(gate * H_DIM + j0 + jj) * 2048;
#pragma unroll
      for (int ks = 0; ks < 8; ++ks)
        whh[nt][ks] = *reinterpret_cast<const f16x8_t*>(Whh + grow + kw + ks * 32 + kfo);
    }
  }

  // ---- per-thread cell state + bias (threads 0..127) ----
  float c_reg = 0.f, cbr0 = 0.f, cbr1 = 0.f, cbr2 = 0.f, cbr3 = 0.f;
  if (tid < 128) {
    const int bb = tid & 15, jj = tid >> 4;
    const int j = j0 + jj;
    c_reg = c0[bb * H_DIM + j];
    cbr0 = bih[0 * H_DIM + j] + bhh[0 * H_DIM + j];
    cbr1 = bih[1 * H_DIM + j] + bhh[1 * H_DIM + j];
    cbr2 = bih[2 * H_DIM + j] + bhh[2 * H_DIM + j];
    cbr3 = bih[3 * H_DIM + j] + bhh[3 * H_DIM + j];
  }

  const size_t arow = (size_t)(lane & 15) * 2048 + kw + (lane >> 4) * 8;

  for (int t = 0; t < L_DIM; ++t) {
    // Gin for this step (plain cached loads; written by a prior kernel)
    float gin0 = 0.f, gin1 = 0.f, gin2 = 0.f, gin3 = 0.f;
    if (tid < 128) {
      const int bb = tid & 15, jj = tid >> 4;
      const size_t gb = ((size_t)t * 16 + bb) * G4 + j0 + jj;
      gin0 = Gin[gb + 0 * H_DIM];
      gin1 = Gin[gb + 1 * H_DIM];
      gin2 = Gin[gb + 2 * H_DIM];
      gin3 = Gin[gb + 3 * H_DIM];
    }

    // h fragments from Xh slot t — coherent IC reads (bypass L1/L2)
    const size_t hoff = (size_t)t * 32768 + arow;
    f16x8_t hf[8];
#pragma unroll
    for (int ks = 0; ks < 8; ++ks)
      hf[ks] = load_f16x8_sc(Xh + hoff + ks * 32);
    asm volatile("s_waitcnt vmcnt(0)" ::: "memory");
    __builtin_amdgcn_sched_barrier(0);   // rule #18: keep MFMAs below the wait

    f32x4_t acc0 = {0.f, 0.f, 0.f, 0.f}, acc1 = {0.f, 0.f, 0.f, 0.f};
#pragma unroll
    for (int ks = 0; ks < 8; ++ks) {
      acc0 = __builtin_amdgcn_mfma_f32_16x16x32_f16(hf[ks], whh[0][ks], acc0, 0, 0, 0);
      acc1 = __builtin_amdgcn_mfma_f32_16x16x32_f16(hf[ks], whh[1][ks], acc1, 0, 0, 0);
    }
#pragma unroll
    for (int r = 0; r < 4; ++r) {
      part[wv][0][(lane >> 4) * 4 + r][lane & 15] = acc0[r];
      part[wv][1][(lane >> 4) * 4 + r][lane & 15] = acc1[r];
    }
    __syncthreads();

    if (tid < 128) {
      const int bb = tid & 15, jj = tid >> 4;
      float g[4] = {gin0, gin1, gin2, gin3};
      const float cb4[4] = {cbr0, cbr1, cbr2, cbr3};
#pragma unroll
      for (int gate = 0; gate < 4; ++gate) {
        const int n = gate * 8 + jj;
        const int ntile = n >> 4, nc = n & 15;
        float s = 0.f;
#pragma unroll
        for (int v = 0; v < 8; ++v) s += part[v][ntile][bb][nc];
        g[gate] += s + cb4[gate];
      }
      const float i_ = sigmoidf_(g[0]);
      const float f_ = sigmoidf_(g[1]);
      const float g_ = tanhf(g[2]);
      const float o_ = sigmoidf_(g[3]);
      c_reg = f_ * c_reg + i_ * g_;
      const float h = o_ * tanhf(c_reg);
      const int bj = bb * 2048 + j0 + jj;
      // write-through (IC) stores: fp16 for recurrence, bf16 hi/lo for FWM
      const _Float16 hF = (_Float16)h;
      const bf16 hhv = f2b(h);
      const bf16 hlv = f2b(h - (float)hhv);
      const size_t xi = ((size_t)t * 16 + bb) * 2048 + j0 + jj;
      store_short_sc(Xh + (size_t)(t + 1) * 32768 + bj,
                     (unsigned int)__builtin_bit_cast(unsigned short, hF));
      store_short_sc(XhHi + xi,
                     (unsigned int)__builtin_bit_cast(unsigned short, hhv));
      store_short_sc(XhLo + xi,
                     (unsigned int)__builtin_bit_cast(unsigned short, hlv));
    }
    // drain write-through stores to IC before publishing arrival
    asm volatile("s_waitcnt vmcnt(0)" ::: "memory");
    __syncthreads();

    if (t < L_DIM - 1) {
      const int target = t + 1;
      if (tid == 0)
        __hip_atomic_store(&flags[wg << 4], target, __ATOMIC_RELAXED,
                           __HIP_MEMORY_SCOPE_AGENT);
      if (tid < NWG) {
        while (__hip_atomic_load(&flags[tid << 4], __ATOMIC_RELAXED,
                                 __HIP_MEMORY_SCOPE_AGENT) < target)
          __builtin_amdgcn_s_sleep(1);
      }
      __syncthreads();
    }
  }
}

// ---------------------------------------------------------------------------
// K3: split-bf16 (hi+lo) NT GEMM — ~fp32 via 3 products (FWM projections).
// MODE 1: C = acc + bias ; MODE 2: C = tanh(acc + bias)
// ---------------------------------------------------------------------------
template <int MODE>
__global__ __launch_bounds__(256) void gemm_nt3(const bf16* __restrict__ A_hi,
                                                const bf16* __restrict__ A_lo,
                                                const bf16* __restrict__ B_hi,
                                                const bf16* __restrict__ B_lo,
                                                const float* __restrict__ bias,
                                                float* __restrict__ C,
                                                int M, int N, int K)
{
  __shared__ __align__(16) bf16 As[2][128 * 32];
  __shared__ __align__(16) bf16 Bs[2][128 * 32];
  const int tid  = threadIdx.x;
  const int lane = tid & 63;
  const int w    = tid >> 6;
  const int wm   = w >> 1, wn = w & 1;
  const int m0   = blockIdx.x * 128, n0 = blockIdx.y * 128;

  f32x4_t acc[4][4];
#pragma unroll
  for (int m = 0; m < 4; ++m)
#pragma unroll
    for (int n = 0; n < 4; ++n) acc[m][n] = (f32x4_t){0.f, 0.f, 0.f, 0.f};

  for (int k0 = 0; k0 < K; k0 += 32) {
#pragma unroll
    for (int r = 0; r < 2; ++r) {
      const int base = w * 2048 + r * 1024;
      const int off  = base + lane * 16;
      const int e    = off >> 1;
      const int row  = e >> 5;
      const int col  = e & 31;
      const size_t gA = (size_t)(m0 + row) * K + (k0 + col);
      const size_t gB = (size_t)(n0 + row) * K + (k0 + col);
      gl_lds16(A_hi + gA, (char*)As[0] + base);
      gl_lds16(A_lo + gA, (char*)As[1] + base);
      gl_lds16(B_hi + gB, (char*)Bs[0] + base);
      gl_lds16(B_lo + gB, (char*)Bs[1] + base);
    }
    __syncthreads();

    bf16x8_t afh[4], afl[4], bfh[4], bfl[4];
    const int kb = (lane >> 4) * 16;
#pragma unroll
    for (int m = 0; m < 4; ++m) {
      const int ro = (wm * 64 + m * 16 + (lane & 15)) * 64 + kb;
      afh[m] = *reinterpret_cast<const bf16x8_t*>((const char*)As[0] + ro);
      afl[m] = *reinterpret_cast<const bf16x8_t*>((const char*)As[1] + ro);
    }
#pragma unroll
    for (int n = 0; n < 4; ++n) {
      const int ro = (wn * 64 + n * 16 + (lane & 15)) * 64 + kb;
      bfh[n] = *reinterpret_cast<const bf16x8_t*>((const char*)Bs[0] + ro);
      bfl[n] = *reinterpret_cast<const bf16x8_t*>((const char*)Bs[1] + ro);
    }
#pragma unroll
    for (int m = 0; m < 4; ++m)
#pragma unroll
      for (int n = 0; n < 4; ++n) {
        acc[m][n] = __builtin_amdgcn_mfma_f32_16x16x32_bf16(afh[m], bfh[n], acc[m][n], 0, 0, 0);
        acc[m][n] = __builtin_amdgcn_mfma_f32_16x16x32_bf16(afh[m], bfl[n], acc[m][n], 0, 0, 0);
        acc[m][n] = __builtin_amdgcn_mfma_f32_16x16x32_bf16(afl[m], bfh[n], acc[m][n], 0, 0, 0);
      }
    __syncthreads();
  }

#pragma unroll
  for (int m = 0; m < 4; ++m) {
#pragma unroll
    for (int n = 0; n < 4; ++n) {
      const int col = n0 + wn * 64 + n * 16 + (lane & 15);
      const float bv = bias[col];
#pragma unroll
      for (int r = 0; r < 4; ++r) {
        const int row = m0 + wm * 64 + m * 16 + (lane >> 4) * 4 + r;
        float v = acc[m][n][r] + bv;
        if (MODE == 2) v = tanhf(v);
        C[(size_t)row * N + col] = v;
      }
    }
  }
}

// ---------------------------------------------------------------------------
// K4a: FWM scan D1 (F-recurrence only). 16 WGs x 512 thr (8 waves — the
// measured-best v2 shape). Wave wv owns t-cols [4wv,4wv+4); lane owns k in
// [16*lane,+16). Per step: LDS staging (2 barriers) + v-reduce (1 barrier) +
// REDUNDANT norm in all waves (no barrier, no wave-0 tail) + F-update +
// G_jit = R_j^T F stored to GLOBAL (fire-and-forget; q-chain moved to K4b).
// 3 barriers/step. Incremental norm (validated rounds 9-10).
// ---------------------------------------------------------------------------
__global__ __launch_bounds__(512, 2) void fwm_scan(const float* __restrict__ Wall,   // (4096,128)
                                                   const float* __restrict__ RVall,  // (4096,128)
                                                   const float* __restrict__ F0,     // (16,1024,32)
                                                   float* __restrict__ Gbuf)         // (4096,3,32,32)
{
  const int b    = blockIdx.x;
  const int tid  = threadIdx.x;
  const int lane = tid & 63;
  const int wv   = tid >> 6;          // 0..7
  const int si    = lane >> 1;        // s-index for this lane's k-range
  const int rbase = 16 * (lane & 1);  // r-index base
  const int tl    = lane & 31;        // t-index for redundant norm phase

  __shared__ float s_s[32], s_r[32], s_tv[32], s_bb;
  __shared__ float s_rv[128];
  __shared__ float s_v[32];
  __shared__ float s_red[8];

  float F[16][4];
#pragma unroll
  for (int i = 0; i < 16; ++i)
#pragma unroll
    for (int j = 0; j < 4; ++j)
      F[i][j] = F0[((size_t)b * 1024 + (16 * lane + i)) * 32 + 4 * wv + j];

  // initial ||F||^2 (one-time full reduce); N maintained redundantly per wave
  float N = 0.f;
  {
    float loc = 0.f;
#pragma unroll
    for (int i = 0; i < 16; ++i)
#pragma unroll
      for (int j = 0; j < 4; ++j) loc += F[i][j] * F[i][j];
#pragma unroll
    for (int m = 1; m < 64; m <<= 1) loc += __shfl_xor(loc, m);
    if (lane == 0) s_red[wv] = loc;
    __syncthreads();
#pragma unroll
    for (int k = 0; k < 8; ++k) N += s_red[k];
  }

  for (int t = 0; t < 256; ++t) {
    const float* wrow  = Wall  + (size_t)(t * 16 + b) * 128;
    const float* rvrow = RVall + (size_t)(t * 16 + b) * 128;
    // prefetch staging values (issued before barrier A: overlaps prev tail)
    float wpre = 0.f, rvpre = 0.f;
    if (tid < 97) wpre = wrow[tid];
    if (tid >= 128 && tid < 256) rvpre = rvrow[tid - 128];
    __syncthreads();                  // A: prior step's s_* readers done
    if (tid < 32)       s_s[tid]       = tanhf(wpre);
    else if (tid < 64)  s_r[tid - 32]  = tanhf(wpre);
    else if (tid < 96)  s_tv[tid - 64] = tanhf(wpre);
    else if (tid == 96) s_bb           = sigmoidf_(wpre + 1.f);
    else if (tid >= 128 && tid < 256) s_rv[tid - 128] = rvpre;
    __syncthreads();                  // B: staging visible

    const float sv = s_s[si];
    float sr[16];
#pragma unroll
    for (int i = 0; i < 16; ++i) sr[i] = sv * s_r[rbase + i];

    // v_t = sum_k sr[k] F[k,t] (4 wave-local t-columns)
    float vv4[4];
#pragma unroll
    for (int j = 0; j < 4; ++j) {
      float pp = 0.f;
#pragma unroll
      for (int i = 0; i < 16; ++i) pp += sr[i] * F[i][j];
#pragma unroll
      for (int m = 1; m < 64; m <<= 1) pp += __shfl_xor(pp, m);
      vv4[j] = pp;
    }
    if (lane == 0) {
#pragma unroll
      for (int j = 0; j < 4; ++j) s_v[4 * wv + j] = vv4[j];
    }
    __syncthreads();                  // C: all v ready

    // redundant norm/u in EVERY wave (staged values are post-activation) —
    // no barrier, no wave-0 serial tail. Identical fp ops => identical inv.
    const float vt  = s_v[tl];
    const float ut  = s_bb * (s_tv[tl] - vt);
    const float sl  = s_s[tl];
    const float rl  = s_r[tl];
    float uv = ut * vt, uu = ut * ut, ss = sl * sl, rr = rl * rl;
#pragma unroll
    for (int m = 1; m < 32; m <<= 1) {
      uv += __shfl_xor(uv, m);
      uu += __shfl_xor(uu, m);
      ss += __shfl_xor(ss, m);
      rr += __shfl_xor(rr, m);
    }
    const float Np  = N + 2.f * uv + ss * rr * uu;
    const float n_  = sqrtf(Np);
    const float inv = 1.f / (fmaxf(n_ - 1.f, 0.f) + 1.f);
    N = Np * inv * inv;

    // u for own cols via in-wave broadcast (lane 4wv+j holds t=4wv+j)
    float uw[4];
#pragma unroll
    for (int j = 0; j < 4; ++j) uw[j] = __shfl(ut, 4 * wv + j);
#pragma unroll
    for (int i = 0; i < 16; ++i)
#pragma unroll
      for (int j = 0; j < 4; ++j)
        F[i][j] = (F[i][j] + sr[i] * uw[j]) * inv;

    // G_jit[i,t] = sum_j rj[j] F[32i+j,t] -> GLOBAL (fire-and-forget)
    float* gout = Gbuf + ((size_t)(t * 16 + b) * 3) * 1024;
#pragma unroll
    for (int jit = 0; jit < 3; ++jit) {
      float rjv[16];
#pragma unroll
      for (int i = 0; i < 16; ++i) rjv[i] = s_rv[32 + 32 * jit + rbase + i];
      f32x4_t gv;
#pragma unroll
      for (int j = 0; j < 4; ++j) {
        float g = 0.f;
#pragma unroll
        for (int i = 0; i < 16; ++i) g += rjv[i] * F[i][j];
        g += __shfl_xor(g, 1);        // combine the two j-halves of row i
        gv[j] = g;
      }
      if ((lane & 1) == 0)
        *reinterpret_cast<f32x4_t*>(gout + jit * 1024 + (lane >> 1) * 32 + 4 * wv) = gv;
    }
    // no barrier here: next iteration's barrier A guards s_* reuse;
    // Gbuf consumed by a later kernel (kernel-boundary coherence).
  }
}

// ---------------------------------------------------------------------------
// K4b: FWM q-readout D2 — 4096 independent (t,b) chains, one wave each.
// q0 = rv[:32]; 3x { c = q·G_jit ; q = LN(c) }. 2 lanes per t-column.
// ---------------------------------------------------------------------------
__global__ __launch_bounds__(256) void fwm_qread(const float* __restrict__ Gbuf,   // (4096,3,32,32)
                                                 const float* __restrict__ RVall,  // (4096,128)
                                                 float* __restrict__ QS)           // (4096,32)
{
  const int pair = blockIdx.x * 4 + (threadIdx.x >> 6);  // t*16+b
  const int lane = threadIdx.x & 63;
  const int tq    = lane & 31;
  const int ihalf = (lane >> 5) * 16;

  const float* G  = Gbuf + (size_t)pair * 3 * 1024;
  float q = RVall[(size_t)pair * 128 + tq];
#pragma unroll 1
  for (int jit = 0; jit < 3; ++jit) {
    float c = 0.f;
#pragma unroll
    for (int i = 0; i < 16; ++i) {
      const float qi = __shfl(q, ihalf + i);   // lanes 0..31 hold q_t
      c += qi * G[jit * 1024 + (ihalf + i) * 32 + tq];
    }
    c += __shfl_xor(c, 32);           // both halves now hold full c_t
    float mval = c;
#pragma unroll
    for (int m = 1; m < 32; m <<= 1) mval += __shfl_xor(mval, m);
    mval *= (1.f / 32.f);
    const float dl = c - mval;
    float var = dl * dl;
#pragma unroll
    for (int m = 1; m < 32; m <<= 1) var += __shfl_xor(var, m);
    var *= (1.f / 32.f);
    q = dl * rsqrtf(var + 1e-5f);
  }
  if (lane < 32) QS[(size_t)pair * 32 + lane] = q;
}

// ---------------------------------------------------------------------------
// K5: out = (XhHi+XhLo) + QS @ Wlin^T + blin
// ---------------------------------------------------------------------------
__global__ __launch_bounds__(256) void out_kernel(const bf16* __restrict__ Xh1Hi,
                                                  const bf16* __restrict__ Xh1Lo,
                                                  const float* __restrict__ QS,
                                                  const float* __restrict__ Wlin,  // (2048,32)
                                                  const float* __restrict__ blin,
                                                  float* __restrict__ out)
{
  __shared__ float qs[32];
  const int row = blockIdx.x;
  if (threadIdx.x < 32) qs[threadIdx.x] = QS[(size_t)row * 32 + threadIdx.x];
  __syncthreads();
  for (int h = threadIdx.x; h < H_DIM; h += 256) {
    const size_t xi = (size_t)row * H_DIM + h;
    float acc = (float)Xh1Hi[xi] + (float)Xh1Lo[xi] + blin[h];
    const float* wr = Wlin + (size_t)h * 32;
#pragma unroll
    for (int t2 = 0; t2 < 32; ++t2) acc += qs[t2] * wr[t2];
    out[xi] = acc;
  }
}

// ---------------------------------------------------------------------------
// Workspace (~237 MB), lifetime-aliased:
//  Whh_f16 33.5 | Wih_f16 33.5 (XhLo aliases after Gin GEMM) |
//  inp_f16 16.8 (XhHi aliases) | Gin 134 (Wall/RVall/QS/Gbuf alias after
//  persist) | Xh_f16 16.9 | Wq/Wr hi/lo 2.1 | flags 16KB | smalls
// ---------------------------------------------------------------------------
extern "C" void kernel_launch(void* const* d_in, const int* in_sizes, int n_in,
                              void* d_out, int out_size, void* d_ws, size_t ws_size,
                              hipStream_t stream)
{
  (void)in_sizes; (void)n_in; (void)out_size; (void)ws_size;
  const float* inp  = (const float*)d_in[0];
  const float* h0   = (const float*)d_in[1];
  const float* c0   = (const float*)d_in[2];
  const float* F0   = (const float*)d_in[3];
  const float* Wih  = (const float*)d_in[4];
  const float* Whh  = (const float*)d_in[5];
  const float* bih  = (const float*)d_in[6];
  const float* bhh  = (const float*)d_in[7];
  const float* Www  = (const float*)d_in[8];
  const float* Wwb  = (const float*)d_in[9];
  const float* Wrw  = (const float*)d_in[10];
  const float* Wrb  = (const float*)d_in[11];
  const float* Wlin = (const float*)d_in[12];
  const float* blin = (const float*)d_in[13];
  float* out = (float*)d_out;

  char* p = (char*)d_ws;
  auto alloc = [&](size_t bytes) {
    char* r = p;
    p += (bytes + 255) & ~(size_t)255;
    return r;
  };
  _Float16* Whh_f = (_Float16*)alloc(16777216ull * 2);   // 33.5 MB
  _Float16* Wih_f = (_Float16*)alloc(16777216ull * 2);   // 33.5 MB
  _Float16* inp_f = (_Float16*)alloc(8388608ull * 2);    // 16.8 MB
  float*    Gin   = (float*)alloc(33554432ull * 4);      // 134 MB (4096x8192)
  _Float16* Xh    = (_Float16*)alloc(257ull * 32768 * 2);// 16.9 MB
  bf16*  Wq_hi  = (bf16*)alloc(262144ull * 2);
  bf16*  Wq_lo  = (bf16*)alloc(262144ull * 2);
  bf16*  Wr_hi  = (bf16*)alloc(262144ull * 2);
  bf16*  Wr_lo  = (bf16*)alloc(262144ull * 2);
  float* wbpad  = (float*)alloc(128ull * 4);
  int*   flags  = (int*)alloc(NWG * 64);                 // 64B line per WG
  // aliases (strictly later lifetimes):
  bf16*  XhHi  = (bf16*)inp_f;          // written by persist after Gin GEMM consumed inp_f
  bf16*  XhLo  = (bf16*)Wih_f;          // written after Wih consumed
  float* Wall  = Gin;                   // 2 MB, written after persist consumed Gin
  float* RVall = Gin + 524288;          // 2 MB
  float* QS    = Gin + 1048576;         // 0.5 MB
  float* Gbuf  = Gin + 2097152;         // 50.3 MB (4096 x 3 x 32 x 32 f32)

  prep_kernel<<<2048, 256, 0, stream>>>(Wih, Whh, inp, Www, Wwb, Wrw, h0,
                                        Wih_f, Whh_f, inp_f,
                                        Wq_hi, Wq_lo, Wr_hi, Wr_lo, wbpad, Xh);

  // Phase A: Gin = x @ W_ih^T + (b_ih + b_hh)   (fp16 inputs, fp32 out)
  gemm_f16<<<dim3(32, 64), 256, 0, stream>>>(inp_f, Wih_f, bih, bhh, Gin,
                                             MROWS, G4, 2048);

  // Phase B: persistent cooperative LSTM (W_hh register-resident, fp16)
  hipMemsetAsync(flags, 0, NWG * 64, stream);
  {
    void* kargs[] = {
      (void*)&Whh_f, (void*)&Gin, (void*)&bih, (void*)&bhh, (void*)&c0,
      (void*)&Xh, (void*)&XhHi, (void*)&XhLo, (void*)&flags
    };
    hipLaunchCooperativeKernel((const void*)lstm_persist, dim3(NWG), dim3(512),
                               kargs, 0, stream);
  }

  // Phase C: FWM projections (~fp32 via split-bf16)
  gemm_nt3<1><<<dim3(32, 1), 256, 0, stream>>>(XhHi, XhLo, Wq_hi, Wq_lo, wbpad,
                                               Wall, MROWS, 128, 2048);
  gemm_nt3<2><<<dim3(32, 1), 256, 0, stream>>>(XhHi, XhLo, Wr_hi, Wr_lo, Wrb,
                                               RVall, MROWS, 128, 2048);

  // Phase D1: FWM F-recurrence scan (8 waves, 3 barriers, G -> global)
  fwm_scan<<<16, 512, 0, stream>>>(Wall, RVall, F0, Gbuf);

  // Phase D2: q-readout — 4096 independent chains, massively parallel
  fwm_qread<<<1024, 256, 0, stream>>>(Gbuf, RVall, QS);

  // Phase E: out = x + QS @ Wlin^T + blin
  out_kernel<<<4096, 256, 0, stream>>>(XhHi, XhLo, QS, Wlin, blin, out);
}

// Round 12
// 2668.488 us; speedup vs baseline: 1.3439x; 1.0042x over previous
//
#include <hip/hip_runtime.h>
#include <hip/hip_bf16.h>
#include <cstdint>
#include <cstddef>

// Problem constants: L=256, B=16, I=2048, H=2048, S=R=T=32
#define L_DIM 256
#define B_DIM 16
#define I_DIM 2048
#define H_DIM 2048
#define G4    8192
#define MROWS 4096
#define NWGL  128            // LSTM workgroups (each owns 16 hidden units)

typedef __hip_bfloat16 bf16;
typedef __bf16 bf16x8_t __attribute__((ext_vector_type(8)));
typedef _Float16 f16x8_t __attribute__((ext_vector_type(8)));
typedef float f32x4_t   __attribute__((ext_vector_type(4)));

__device__ __forceinline__ bf16 f2b(float f) { return __float2bfloat16(f); }

__device__ __forceinline__ void gl_lds16(const void* g, void* l) {
  __builtin_amdgcn_global_load_lds(
      (const __attribute__((address_space(1))) unsigned int*)g,
      (__attribute__((address_space(3))) unsigned int*)l, 16, 0, 0);
}

__device__ __forceinline__ float sigmoidf_(float x) { return 1.f / (1.f + expf(-x)); }

// Coherent (IC-through) access helpers — same hardware path the working
// flag protocol uses (sc1 store -> IC, sc1 load <- IC), widened to data.
__device__ __forceinline__ f16x8_t load_f16x8_sc(const _Float16* p) {
  f16x8_t r;
  asm volatile("global_load_dwordx4 %0, %1, off sc0 sc1" : "=v"(r) : "v"(p));
  return r;
}
__device__ __forceinline__ void store_short_sc(void* p, unsigned int v) {
  asm volatile("global_store_short %0, %1, off sc0 sc1" :: "v"(p), "v"(v) : "memory");
}

// ---------------------------------------------------------------------------
// K0: prep — fp16 casts (LSTM path), bf16 hi/lo (FWM weights), h0 fp16
// ---------------------------------------------------------------------------
__global__ void prep_kernel(const float* __restrict__ Wih, const float* __restrict__ Whh,
                            const float* __restrict__ inp, const float* __restrict__ Www,
                            const float* __restrict__ Wwb, const float* __restrict__ Wrw,
                            const float* __restrict__ h0,
                            _Float16* __restrict__ Wih_f, _Float16* __restrict__ Whh_f,
                            _Float16* __restrict__ inp_f,
                            bf16* __restrict__ Wq_hi, bf16* __restrict__ Wq_lo,
                            bf16* __restrict__ Wr_hi, bf16* __restrict__ Wr_lo,
                            float* __restrict__ wbpad,
                            _Float16* __restrict__ Xh0)
{
  size_t idx0 = (size_t)blockIdx.x * blockDim.x + threadIdx.x;
  size_t stride = (size_t)gridDim.x * blockDim.x;
  for (size_t i = idx0; i < 16777216ull; i += stride) {
    Wih_f[i] = (_Float16)Wih[i];
    Whh_f[i] = (_Float16)Whh[i];
  }
  for (size_t i = idx0; i < 8388608ull; i += stride) inp_f[i] = (_Float16)inp[i];
  for (size_t i = idx0; i < 262144ull; i += stride) {
    size_t r = i >> 11;
    float q = (r < 97) ? Www[i] : 0.f;
    bf16 qh = f2b(q);
    Wq_hi[i] = qh;
    Wq_lo[i] = f2b(q - (float)qh);
    float rr = Wrw[i];
    bf16 rh = f2b(rr);
    Wr_hi[i] = rh;
    Wr_lo[i] = f2b(rr - (float)rh);
  }
  for (size_t i = idx0; i < 128ull; i += stride) wbpad[i] = (i < 97) ? Wwb[i] : 0.f;
  for (size_t i = idx0; i < 32768ull; i += stride) Xh0[i] = (_Float16)h0[i];
}

// ---------------------------------------------------------------------------
// K1: fp16 NT GEMM  C = A * B^T + bias, output written in LSTM-transposed
// layout Gin2[t][wg][gate][jj][bb]  (wg=j>>4, jj=j&15; 4KB contiguous/WG/t)
// ---------------------------------------------------------------------------
__global__ __launch_bounds__(256) void gemm_f16(const _Float16* __restrict__ A,
                                                const _Float16* __restrict__ B,
                                                const float* __restrict__ bih,
                                                const float* __restrict__ bhh,
                                                float* __restrict__ Gin2,
                                                int M, int N, int K)
{
  __shared__ __align__(16) _Float16 As[128 * 32];
  __shared__ __align__(16) _Float16 Bs[128 * 32];
  const int tid  = threadIdx.x;
  const int lane = tid & 63;
  const int w    = tid >> 6;
  const int wm   = w >> 1, wn = w & 1;
  const int m0   = blockIdx.x * 128, n0 = blockIdx.y * 128;

  f32x4_t acc[4][4];
#pragma unroll
  for (int m = 0; m < 4; ++m)
#pragma unroll
    for (int n = 0; n < 4; ++n) acc[m][n] = (f32x4_t){0.f, 0.f, 0.f, 0.f};

  for (int k0 = 0; k0 < K; k0 += 32) {
#pragma unroll
    for (int r = 0; r < 2; ++r) {
      const int base = w * 2048 + r * 1024;
      const int off  = base + lane * 16;
      const int e    = off >> 1;
      const int row  = e >> 5;
      const int col  = e & 31;
      gl_lds16(A + (size_t)(m0 + row) * K + (k0 + col), (char*)As + base);
      gl_lds16(B + (size_t)(n0 + row) * K + (k0 + col), (char*)Bs + base);
    }
    __syncthreads();

    f16x8_t af[4], bfr[4];
    const int kb = (lane >> 4) * 16;
#pragma unroll
    for (int m = 0; m < 4; ++m)
      af[m] = *reinterpret_cast<const f16x8_t*>((const char*)As + (wm * 64 + m * 16 + (lane & 15)) * 64 + kb);
#pragma unroll
    for (int n = 0; n < 4; ++n)
      bfr[n] = *reinterpret_cast<const f16x8_t*>((const char*)Bs + (wn * 64 + n * 16 + (lane & 15)) * 64 + kb);
#pragma unroll
    for (int m = 0; m < 4; ++m)
#pragma unroll
      for (int n = 0; n < 4; ++n)
        acc[m][n] = __builtin_amdgcn_mfma_f32_16x16x32_f16(af[m], bfr[n], acc[m][n], 0, 0, 0);
    __syncthreads();
  }

#pragma unroll
  for (int m = 0; m < 4; ++m) {
#pragma unroll
    for (int n = 0; n < 4; ++n) {
      const int col  = n0 + wn * 64 + n * 16 + (lane & 15);
      const float bv = bih[col] + bhh[col];
      const int gate = col >> 11, j = col & 2047;
      const int wg = j >> 4, jj = j & 15;
#pragma unroll
      for (int r = 0; r < 4; ++r) {
        const int row = m0 + wm * 64 + m * 16 + (lane >> 4) * 4 + r;
        const int t = row >> 4, bb = row & 15;
        const size_t idx = ((((size_t)t * NWGL + wg) * 4 + gate) * 16 + jj) * 16 + bb;
        Gin2[idx] = acc[m][n][r] + bv;
      }
    }
  }
}

// ---------------------------------------------------------------------------
// K2: persistent LSTM. 128 WGs x 512 thr (8 waves), cooperative.
// WG owns 16 hidden units (4 gate tiles of 16 rows); wave wv owns K-slice
// [256wv,+256). W_hh fp16 frags register-resident (128 VGPR/lane).
// Fence-free IC h-exchange (round 8). Gin read is 4x1KB coalesced (Gin2).
// ---------------------------------------------------------------------------
__global__ __launch_bounds__(512, 2) void lstm_persist(
    const _Float16* __restrict__ Whh,
    const float* __restrict__ Gin2,     // (256,128,4,16,16)
    const float* __restrict__ bih, const float* __restrict__ bhh,
    const float* __restrict__ c0,
    _Float16* __restrict__ Xh,          // 257 slots (16,2048) fp16
    bf16* __restrict__ XhHi, bf16* __restrict__ XhLo,  // 256 slots
    int* flags)                          // NWGL x 16 ints (64B stride)
{
  const int tid  = threadIdx.x;
  const int lane = tid & 63;
  const int wv   = tid >> 6;          // 0..7
  const int wg   = blockIdx.x;        // 0..127
  const int j0   = wg * 16;
  const int kw   = wv * 256;

  __shared__ float part[8][4][16][17];   // [wave][gate][batch][jj] padded

  // ---- register-resident W_hh fragments: tile g = gate, col nn = jj ----
  f16x8_t whh[4][8];
  {
    const int nn  = lane & 15;
    const int kfo = (lane >> 4) * 8;
#pragma unroll
    for (int g = 0; g < 4; ++g) {
      const size_t grow = (size_t)(g * H_DIM + j0 + nn) * 2048;
#pragma unroll
      for (int ks = 0; ks < 8; ++ks)
        whh[g][ks] = *reinterpret_cast<const f16x8_t*>(Whh + grow + kw + ks * 32 + kfo);
    }
  }

  // ---- per-thread cell state + bias (threads 0..255: bb=tid&15, jj=tid>>4) ----
  float c_reg = 0.f, cbr0 = 0.f, cbr1 = 0.f, cbr2 = 0.f, cbr3 = 0.f;
  if (tid < 256) {
    const int bb = tid & 15, jj = tid >> 4;
    const int j = j0 + jj;
    c_reg = c0[bb * H_DIM + j];
    cbr0 = bih[0 * H_DIM + j] + bhh[0 * H_DIM + j];
    cbr1 = bih[1 * H_DIM + j] + bhh[1 * H_DIM + j];
    cbr2 = bih[2 * H_DIM + j] + bhh[2 * H_DIM + j];
    cbr3 = bih[3 * H_DIM + j] + bhh[3 * H_DIM + j];
  }

  const size_t arow = (size_t)(lane & 15) * 2048 + kw + (lane >> 4) * 8;

  for (int t = 0; t < L_DIM; ++t) {
    // Gin2 for this step: 4 coalesced 1KB blocks per WG
    float gin0 = 0.f, gin1 = 0.f, gin2v = 0.f, gin3 = 0.f;
    if (tid < 256) {
      const float* gbase = Gin2 + ((size_t)t * NWGL + wg) * 1024;
      gin0  = gbase[0 * 256 + tid];
      gin1  = gbase[1 * 256 + tid];
      gin2v = gbase[2 * 256 + tid];
      gin3  = gbase[3 * 256 + tid];
    }

    // h fragments from Xh slot t — coherent IC reads (bypass L1/L2)
    const size_t hoff = (size_t)t * 32768 + arow;
    f16x8_t hf[8];
#pragma unroll
    for (int ks = 0; ks < 8; ++ks)
      hf[ks] = load_f16x8_sc(Xh + hoff + ks * 32);
    asm volatile("s_waitcnt vmcnt(0)" ::: "memory");
    __builtin_amdgcn_sched_barrier(0);   // rule #18: keep MFMAs below the wait

    f32x4_t acc[4];
#pragma unroll
    for (int g = 0; g < 4; ++g) acc[g] = (f32x4_t){0.f, 0.f, 0.f, 0.f};
#pragma unroll
    for (int ks = 0; ks < 8; ++ks) {
#pragma unroll
      for (int g = 0; g < 4; ++g)
        acc[g] = __builtin_amdgcn_mfma_f32_16x16x32_f16(hf[ks], whh[g][ks], acc[g], 0, 0, 0);
    }
#pragma unroll
    for (int g = 0; g < 4; ++g)
#pragma unroll
      for (int r = 0; r < 4; ++r)
        part[wv][g][(lane >> 4) * 4 + r][lane & 15] = acc[g][r];
    __syncthreads();

    if (tid < 256) {
      const int bb = tid & 15, jj = tid >> 4;
      float g4[4] = {gin0, gin1, gin2v, gin3};
      const float cb4[4] = {cbr0, cbr1, cbr2, cbr3};
#pragma unroll
      for (int g = 0; g < 4; ++g) {
        float s = 0.f;
#pragma unroll
        for (int v = 0; v < 8; ++v) s += part[v][g][bb][jj];
        g4[g] += s + cb4[g];
      }
      const float i_ = sigmoidf_(g4[0]);
      const float f_ = sigmoidf_(g4[1]);
      const float g_ = tanhf(g4[2]);
      const float o_ = sigmoidf_(g4[3]);
      c_reg = f_ * c_reg + i_ * g_;
      const float h = o_ * tanhf(c_reg);
      const int bj = bb * 2048 + j0 + jj;
      const _Float16 hF = (_Float16)h;
      const bf16 hhv = f2b(h);
      const bf16 hlv = f2b(h - (float)hhv);
      const size_t xi = ((size_t)t * 16 + bb) * 2048 + j0 + jj;
      store_short_sc(Xh + (size_t)(t + 1) * 32768 + bj,
                     (unsigned int)__builtin_bit_cast(unsigned short, hF));
      store_short_sc(XhHi + xi,
                     (unsigned int)__builtin_bit_cast(unsigned short, hhv));
      store_short_sc(XhLo + xi,
                     (unsigned int)__builtin_bit_cast(unsigned short, hlv));
    }
    // drain write-through stores to IC before publishing arrival
    asm volatile("s_waitcnt vmcnt(0)" ::: "memory");
    __syncthreads();

    if (t < L_DIM - 1) {
      const int target = t + 1;
      if (tid == 0)
        __hip_atomic_store(&flags[wg << 4], target, __ATOMIC_RELAXED,
                           __HIP_MEMORY_SCOPE_AGENT);
      if (tid < NWGL) {
        while (__hip_atomic_load(&flags[tid << 4], __ATOMIC_RELAXED,
                                 __HIP_MEMORY_SCOPE_AGENT) < target)
          __builtin_amdgcn_s_sleep(1);
      }
      __syncthreads();
    }
  }
}

// ---------------------------------------------------------------------------
// K3: split-bf16 (hi+lo) NT GEMM — ~fp32 via 3 products (FWM projections).
// MODE 1: C = acc + bias ; MODE 2: C = tanh(acc + bias)
// ---------------------------------------------------------------------------
template <int MODE>
__global__ __launch_bounds__(256) void gemm_nt3(const bf16* __restrict__ A_hi,
                                                const bf16* __restrict__ A_lo,
                                                const bf16* __restrict__ B_hi,
                                                const bf16* __restrict__ B_lo,
                                                const float* __restrict__ bias,
                                                float* __restrict__ C,
                                                int M, int N, int K)
{
  __shared__ __align__(16) bf16 As[2][128 * 32];
  __shared__ __align__(16) bf16 Bs[2][128 * 32];
  const int tid  = threadIdx.x;
  const int lane = tid & 63;
  const int w    = tid >> 6;
  const int wm   = w >> 1, wn = w & 1;
  const int m0   = blockIdx.x * 128, n0 = blockIdx.y * 128;

  f32x4_t acc[4][4];
#pragma unroll
  for (int m = 0; m < 4; ++m)
#pragma unroll
    for (int n = 0; n < 4; ++n) acc[m][n] = (f32x4_t){0.f, 0.f, 0.f, 0.f};

  for (int k0 = 0; k0 < K; k0 += 32) {
#pragma unroll
    for (int r = 0; r < 2; ++r) {
      const int base = w * 2048 + r * 1024;
      const int off  = base + lane * 16;
      const int e    = off >> 1;
      const int row  = e >> 5;
      const int col  = e & 31;
      const size_t gA = (size_t)(m0 + row) * K + (k0 + col);
      const size_t gB = (size_t)(n0 + row) * K + (k0 + col);
      gl_lds16(A_hi + gA, (char*)As[0] + base);
      gl_lds16(A_lo + gA, (char*)As[1] + base);
      gl_lds16(B_hi + gB, (char*)Bs[0] + base);
      gl_lds16(B_lo + gB, (char*)Bs[1] + base);
    }
    __syncthreads();

    bf16x8_t afh[4], afl[4], bfh[4], bfl[4];
    const int kb = (lane >> 4) * 16;
#pragma unroll
    for (int m = 0; m < 4; ++m) {
      const int ro = (wm * 64 + m * 16 + (lane & 15)) * 64 + kb;
      afh[m] = *reinterpret_cast<const bf16x8_t*>((const char*)As[0] + ro);
      afl[m] = *reinterpret_cast<const bf16x8_t*>((const char*)As[1] + ro);
    }
#pragma unroll
    for (int n = 0; n < 4; ++n) {
      const int ro = (wn * 64 + n * 16 + (lane & 15)) * 64 + kb;
      bfh[n] = *reinterpret_cast<const bf16x8_t*>((const char*)Bs[0] + ro);
      bfl[n] = *reinterpret_cast<const bf16x8_t*>((const char*)Bs[1] + ro);
    }
#pragma unroll
    for (int m = 0; m < 4; ++m)
#pragma unroll
      for (int n = 0; n < 4; ++n) {
        acc[m][n] = __builtin_amdgcn_mfma_f32_16x16x32_bf16(afh[m], bfh[n], acc[m][n], 0, 0, 0);
        acc[m][n] = __builtin_amdgcn_mfma_f32_16x16x32_bf16(afh[m], bfl[n], acc[m][n], 0, 0, 0);
        acc[m][n] = __builtin_amdgcn_mfma_f32_16x16x32_bf16(afl[m], bfh[n], acc[m][n], 0, 0, 0);
      }
    __syncthreads();
  }

#pragma unroll
  for (int m = 0; m < 4; ++m) {
#pragma unroll
    for (int n = 0; n < 4; ++n) {
      const int col = n0 + wn * 64 + n * 16 + (lane & 15);
      const float bv = bias[col];
#pragma unroll
      for (int r = 0; r < 4; ++r) {
        const int row = m0 + wm * 64 + m * 16 + (lane >> 4) * 4 + r;
        float v = acc[m][n][r] + bv;
        if (MODE == 2) v = tanhf(v);
        C[(size_t)row * N + col] = v;
      }
    }
  }
}

// ---------------------------------------------------------------------------
// K4a: FWM scan D1 (F-recurrence). 16 WGs x 512 thr (8 waves). Parity
// double-buffered LDS staging -> 2 barriers/step. Redundant per-wave norm
// (no barrier). G_jit -> global (fire-and-forget; q-chain in K4b).
// ---------------------------------------------------------------------------
__global__ __launch_bounds__(512, 2) void fwm_scan(const float* __restrict__ Wall,   // (4096,128)
                                                   const float* __restrict__ RVall,  // (4096,128)
                                                   const float* __restrict__ F0,     // (16,1024,32)
                                                   float* __restrict__ Gbuf)         // (4096,3,32,32)
{
  const int b    = blockIdx.x;
  const int tid  = threadIdx.x;
  const int lane = tid & 63;
  const int wv   = tid >> 6;          // 0..7
  const int si    = lane >> 1;        // s-index for this lane's k-range
  const int rbase = 16 * (lane & 1);  // r-index base
  const int tl    = lane & 31;        // t-index for redundant norm phase

  __shared__ float s_s[2][32], s_r[2][32], s_tv[2][32], s_bb[2];
  __shared__ float s_rv[2][128];
  __shared__ float s_v[32];
  __shared__ float s_red[8];

  float F[16][4];
#pragma unroll
  for (int i = 0; i < 16; ++i)
#pragma unroll
    for (int j = 0; j < 4; ++j)
      F[i][j] = F0[((size_t)b * 1024 + (16 * lane + i)) * 32 + 4 * wv + j];

  // initial ||F||^2 (one-time full reduce); N maintained redundantly per wave
  float N = 0.f;
  {
    float loc = 0.f;
#pragma unroll
    for (int i = 0; i < 16; ++i)
#pragma unroll
      for (int j = 0; j < 4; ++j) loc += F[i][j] * F[i][j];
#pragma unroll
    for (int m = 1; m < 64; m <<= 1) loc += __shfl_xor(loc, m);
    if (lane == 0) s_red[wv] = loc;
    __syncthreads();
#pragma unroll
    for (int k = 0; k < 8; ++k) N += s_red[k];
  }

  // prefetch t=0
  float wpre = 0.f, rvpre = 0.f;
  if (tid < 97) wpre = Wall[(size_t)b * 128 + tid];
  if (tid >= 128 && tid < 256) rvpre = RVall[(size_t)b * 128 + tid - 128];

  for (int t = 0; t < 256; ++t) {
    const int par = t & 1;
    // stage parity-p buffers (prior readers of this parity finished at t-2;
    // separated by both barriers of t-1)
    if (tid < 32)       s_s[par][tid]       = tanhf(wpre);
    else if (tid < 64)  s_r[par][tid - 32]  = tanhf(wpre);
    else if (tid < 96)  s_tv[par][tid - 64] = tanhf(wpre);
    else if (tid == 96) s_bb[par]           = sigmoidf_(wpre + 1.f);
    else if (tid >= 128 && tid < 256) s_rv[par][tid - 128] = rvpre;
    __syncthreads();                  // 1: staging visible

    // prefetch t+1 (overlaps compute)
    if (t < 255) {
      const float* wrow2  = Wall  + (size_t)((t + 1) * 16 + b) * 128;
      const float* rvrow2 = RVall + (size_t)((t + 1) * 16 + b) * 128;
      if (tid < 97) wpre = wrow2[tid];
      if (tid >= 128 && tid < 256) rvpre = rvrow2[tid - 128];
    }

    const float sv = s_s[par][si];
    float sr[16];
#pragma unroll
    for (int i = 0; i < 16; ++i) sr[i] = sv * s_r[par][rbase + i];

    // v_t = sum_k sr[k] F[k,t] (4 wave-local t-columns)
    float vv4[4];
#pragma unroll
    for (int j = 0; j < 4; ++j) {
      float pp = 0.f;
#pragma unroll
      for (int i = 0; i < 16; ++i) pp += sr[i] * F[i][j];
#pragma unroll
      for (int m = 1; m < 64; m <<= 1) pp += __shfl_xor(pp, m);
      vv4[j] = pp;
    }
    if (lane == 0) {
#pragma unroll
      for (int j = 0; j < 4; ++j) s_v[4 * wv + j] = vv4[j];
    }
    __syncthreads();                  // 2: all v ready

    // redundant norm/u in EVERY wave — no barrier, no wave-0 tail
    const float vt  = s_v[tl];
    const float ut  = s_bb[par] * (s_tv[par][tl] - vt);
    const float sl  = s_s[par][tl];
    const float rl  = s_r[par][tl];
    float uv = ut * vt, uu = ut * ut, ss = sl * sl, rr = rl * rl;
#pragma unroll
    for (int m = 1; m < 32; m <<= 1) {
      uv += __shfl_xor(uv, m);
      uu += __shfl_xor(uu, m);
      ss += __shfl_xor(ss, m);
      rr += __shfl_xor(rr, m);
    }
    const float Np  = N + 2.f * uv + ss * rr * uu;
    const float n_  = sqrtf(Np);
    const float inv = 1.f / (fmaxf(n_ - 1.f, 0.f) + 1.f);
    N = Np * inv * inv;

    // u for own cols via in-wave broadcast (lane 4wv+j holds t=4wv+j)
    float uw[4];
#pragma unroll
    for (int j = 0; j < 4; ++j) uw[j] = __shfl(ut, 4 * wv + j);
#pragma unroll
    for (int i = 0; i < 16; ++i)
#pragma unroll
      for (int j = 0; j < 4; ++j)
        F[i][j] = (F[i][j] + sr[i] * uw[j]) * inv;

    // G_jit[i,t] = sum_j rj[j] F[32i+j,t] -> GLOBAL (fire-and-forget)
    float* gout = Gbuf + ((size_t)(t * 16 + b) * 3) * 1024;
#pragma unroll
    for (int jit = 0; jit < 3; ++jit) {
      float rjv[16];
#pragma unroll
      for (int i = 0; i < 16; ++i) rjv[i] = s_rv[par][32 + 32 * jit + rbase + i];
      f32x4_t gv;
#pragma unroll
      for (int j = 0; j < 4; ++j) {
        float g = 0.f;
#pragma unroll
        for (int i = 0; i < 16; ++i) g += rjv[i] * F[i][j];
        g += __shfl_xor(g, 1);        // combine the two j-halves of row i
        gv[j] = g;
      }
      if ((lane & 1) == 0)
        *reinterpret_cast<f32x4_t*>(gout + jit * 1024 + (lane >> 1) * 32 + 4 * wv) = gv;
    }
    // no trailing barrier: next step stages the OTHER parity; s_v write for
    // t+1 happens after barrier 1 of t+1, read of s_v here precedes it.
  }
}

// ---------------------------------------------------------------------------
// K4b: FWM q-readout D2 — 4096 independent (t,b) chains, one wave each.
// ---------------------------------------------------------------------------
__global__ __launch_bounds__(256) void fwm_qread(const float* __restrict__ Gbuf,   // (4096,3,32,32)
                                                 const float* __restrict__ RVall,  // (4096,128)
                                                 float* __restrict__ QS)           // (4096,32)
{
  const int pair = blockIdx.x * 4 + (threadIdx.x >> 6);  // t*16+b
  const int lane = threadIdx.x & 63;
  const int tq    = lane & 31;
  const int ihalf = (lane >> 5) * 16;

  const float* G  = Gbuf + (size_t)pair * 3 * 1024;
  float q = RVall[(size_t)pair * 128 + tq];
#pragma unroll 1
  for (int jit = 0; jit < 3; ++jit) {
    float c = 0.f;
#pragma unroll
    for (int i = 0; i < 16; ++i) {
      const float qi = __shfl(q, ihalf + i);   // lanes 0..31 hold q_t
      c += qi * G[jit * 1024 + (ihalf + i) * 32 + tq];
    }
    c += __shfl_xor(c, 32);           // both halves now hold full c_t
    float mval = c;
#pragma unroll
    for (int m = 1; m < 32; m <<= 1) mval += __shfl_xor(mval, m);
    mval *= (1.f / 32.f);
    const float dl = c - mval;
    float var = dl * dl;
#pragma unroll
    for (int m = 1; m < 32; m <<= 1) var += __shfl_xor(var, m);
    var *= (1.f / 32.f);
    q = dl * rsqrtf(var + 1e-5f);
  }
  if (lane < 32) QS[(size_t)pair * 32 + lane] = q;
}

// ---------------------------------------------------------------------------
// K5: out = (XhHi+XhLo) + QS @ Wlin^T + blin
// ---------------------------------------------------------------------------
__global__ __launch_bounds__(256) void out_kernel(const bf16* __restrict__ Xh1Hi,
                                                  const bf16* __restrict__ Xh1Lo,
                                                  const float* __restrict__ QS,
                                                  const float* __restrict__ Wlin,  // (2048,32)
                                                  const float* __restrict__ blin,
                                                  float* __restrict__ out)
{
  __shared__ float qs[32];
  const int row = blockIdx.x;
  if (threadIdx.x < 32) qs[threadIdx.x] = QS[(size_t)row * 32 + threadIdx.x];
  __syncthreads();
  for (int h = threadIdx.x; h < H_DIM; h += 256) {
    const size_t xi = (size_t)row * H_DIM + h;
    float acc = (float)Xh1Hi[xi] + (float)Xh1Lo[xi] + blin[h];
    const float* wr = Wlin + (size_t)h * 32;
#pragma unroll
    for (int t2 = 0; t2 < 32; ++t2) acc += qs[t2] * wr[t2];
    out[xi] = acc;
  }
}

// ---------------------------------------------------------------------------
// Workspace (~237 MB), lifetime-aliased (unchanged layout from round 11).
// ---------------------------------------------------------------------------
extern "C" void kernel_launch(void* const* d_in, const int* in_sizes, int n_in,
                              void* d_out, int out_size, void* d_ws, size_t ws_size,
                              hipStream_t stream)
{
  (void)in_sizes; (void)n_in; (void)out_size; (void)ws_size;
  const float* inp  = (const float*)d_in[0];
  const float* h0   = (const float*)d_in[1];
  const float* c0   = (const float*)d_in[2];
  const float* F0   = (const float*)d_in[3];
  const float* Wih  = (const float*)d_in[4];
  const float* Whh  = (const float*)d_in[5];
  const float* bih  = (const float*)d_in[6];
  const float* bhh  = (const float*)d_in[7];
  const float* Www  = (const float*)d_in[8];
  const float* Wwb  = (const float*)d_in[9];
  const float* Wrw  = (const float*)d_in[10];
  const float* Wrb  = (const float*)d_in[11];
  const float* Wlin = (const float*)d_in[12];
  const float* blin = (const float*)d_in[13];
  float* out = (float*)d_out;

  char* p = (char*)d_ws;
  auto alloc = [&](size_t bytes) {
    char* r = p;
    p += (bytes + 255) & ~(size_t)255;
    return r;
  };
  _Float16* Whh_f = (_Float16*)alloc(16777216ull * 2);   // 33.5 MB
  _Float16* Wih_f = (_Float16*)alloc(16777216ull * 2);   // 33.5 MB
  _Float16* inp_f = (_Float16*)alloc(8388608ull * 2);    // 16.8 MB
  float*    Gin   = (float*)alloc(33554432ull * 4);      // 134 MB (Gin2 layout)
  _Float16* Xh    = (_Float16*)alloc(257ull * 32768 * 2);// 16.9 MB
  bf16*  Wq_hi  = (bf16*)alloc(262144ull * 2);
  bf16*  Wq_lo  = (bf16*)alloc(262144ull * 2);
  bf16*  Wr_hi  = (bf16*)alloc(262144ull * 2);
  bf16*  Wr_lo  = (bf16*)alloc(262144ull * 2);
  float* wbpad  = (float*)alloc(128ull * 4);
  int*   flags  = (int*)alloc(NWGL * 64);                // 64B line per WG
  // aliases (strictly later lifetimes):
  bf16*  XhHi  = (bf16*)inp_f;          // written by persist after Gin GEMM consumed inp_f
  bf16*  XhLo  = (bf16*)Wih_f;          // written after Wih consumed
  float* Wall  = Gin;                   // 2 MB, written after persist consumed Gin
  float* RVall = Gin + 524288;          // 2 MB
  float* QS    = Gin + 1048576;         // 0.5 MB
  float* Gbuf  = Gin + 2097152;         // 50.3 MB (4096 x 3 x 32 x 32 f32)

  prep_kernel<<<2048, 256, 0, stream>>>(Wih, Whh, inp, Www, Wwb, Wrw, h0,
                                        Wih_f, Whh_f, inp_f,
                                        Wq_hi, Wq_lo, Wr_hi, Wr_lo, wbpad, Xh);

  // Phase A: Gin2 = x @ W_ih^T + bias, in LSTM-transposed layout
  gemm_f16<<<dim3(32, 64), 256, 0, stream>>>(inp_f, Wih_f, bih, bhh, Gin,
                                             MROWS, G4, 2048);

  // Phase B: persistent cooperative LSTM (128 WGs, W_hh register-resident)
  hipMemsetAsync(flags, 0, NWGL * 64, stream);
  {
    void* kargs[] = {
      (void*)&Whh_f, (void*)&Gin, (void*)&bih, (void*)&bhh, (void*)&c0,
      (void*)&Xh, (void*)&XhHi, (void*)&XhLo, (void*)&flags
    };
    hipLaunchCooperativeKernel((const void*)lstm_persist, dim3(NWGL), dim3(512),
                               kargs, 0, stream);
  }

  // Phase C: FWM projections (~fp32 via split-bf16)
  gemm_nt3<1><<<dim3(32, 1), 256, 0, stream>>>(XhHi, XhLo, Wq_hi, Wq_lo, wbpad,
                                               Wall, MROWS, 128, 2048);
  gemm_nt3<2><<<dim3(32, 1), 256, 0, stream>>>(XhHi, XhLo, Wr_hi, Wr_lo, Wrb,
                                               RVall, MROWS, 128, 2048);

  // Phase D1: FWM F-recurrence scan (8 waves, 2 barriers/step, G -> global)
  fwm_scan<<<16, 512, 0, stream>>>(Wall, RVall, F0, Gbuf);

  // Phase D2: q-readout — 4096 independent chains, massively parallel
  fwm_qread<<<1024, 256, 0, stream>>>(Gbuf, RVall, QS);

  // Phase E: out = x + QS @ Wlin^T + blin
  out_kernel<<<4096, 256, 0, stream>>>(XhHi, XhLo, QS, Wlin, blin, out);
}

// Round 13
// 2548.423 us; speedup vs baseline: 1.4072x; 1.0471x over previous
//
#include <hip/hip_runtime.h>
#include <hip/hip_bf16.h>
#include <cstdint>
#include <cstddef>

// Problem constants: L=256, B=16, I=2048, H=2048, S=R=T=32
#define L_DIM 256
#define B_DIM 16
#define I_DIM 2048
#define H_DIM 2048
#define G4    8192
#define MROWS 4096
#define NWGL  128            // LSTM workgroups (each owns 16 hidden units)

typedef __hip_bfloat16 bf16;
typedef __bf16 bf16x8_t __attribute__((ext_vector_type(8)));
typedef _Float16 f16x8_t __attribute__((ext_vector_type(8)));
typedef float f32x4_t   __attribute__((ext_vector_type(4)));

__device__ __forceinline__ bf16 f2b(float f) { return __float2bfloat16(f); }

__device__ __forceinline__ void gl_lds16(const void* g, void* l) {
  __builtin_amdgcn_global_load_lds(
      (const __attribute__((address_space(1))) unsigned int*)g,
      (__attribute__((address_space(3))) unsigned int*)l, 16, 0, 0);
}

__device__ __forceinline__ float sigmoidf_(float x) { return 1.f / (1.f + expf(-x)); }

// Coherent (IC-through) access helpers — same hardware path the working
// flag protocol uses (sc1 store -> IC, sc1 load <- IC), widened to data.
__device__ __forceinline__ f16x8_t load_f16x8_sc(const _Float16* p) {
  f16x8_t r;
  asm volatile("global_load_dwordx4 %0, %1, off sc0 sc1" : "=v"(r) : "v"(p));
  return r;
}
__device__ __forceinline__ void store_short_sc(void* p, unsigned int v) {
  asm volatile("global_store_short %0, %1, off sc0 sc1" :: "v"(p), "v"(v) : "memory");
}

// ---------------------------------------------------------------------------
// K0: prep — fp16 casts (LSTM path), bf16 hi/lo (FWM weights), h0 fp16
// ---------------------------------------------------------------------------
__global__ void prep_kernel(const float* __restrict__ Wih, const float* __restrict__ Whh,
                            const float* __restrict__ inp, const float* __restrict__ Www,
                            const float* __restrict__ Wwb, const float* __restrict__ Wrw,
                            const float* __restrict__ h0,
                            _Float16* __restrict__ Wih_f, _Float16* __restrict__ Whh_f,
                            _Float16* __restrict__ inp_f,
                            bf16* __restrict__ Wq_hi, bf16* __restrict__ Wq_lo,
                            bf16* __restrict__ Wr_hi, bf16* __restrict__ Wr_lo,
                            float* __restrict__ wbpad,
                            _Float16* __restrict__ Xh0)
{
  size_t idx0 = (size_t)blockIdx.x * blockDim.x + threadIdx.x;
  size_t stride = (size_t)gridDim.x * blockDim.x;
  for (size_t i = idx0; i < 16777216ull; i += stride) {
    Wih_f[i] = (_Float16)Wih[i];
    Whh_f[i] = (_Float16)Whh[i];
  }
  for (size_t i = idx0; i < 8388608ull; i += stride) inp_f[i] = (_Float16)inp[i];
  for (size_t i = idx0; i < 262144ull; i += stride) {
    size_t r = i >> 11;
    float q = (r < 97) ? Www[i] : 0.f;
    bf16 qh = f2b(q);
    Wq_hi[i] = qh;
    Wq_lo[i] = f2b(q - (float)qh);
    float rr = Wrw[i];
    bf16 rh = f2b(rr);
    Wr_hi[i] = rh;
    Wr_lo[i] = f2b(rr - (float)rh);
  }
  for (size_t i = idx0; i < 128ull; i += stride) wbpad[i] = (i < 97) ? Wwb[i] : 0.f;
  for (size_t i = idx0; i < 32768ull; i += stride) Xh0[i] = (_Float16)h0[i];
}

// ---------------------------------------------------------------------------
// K1: fp16 NT GEMM  C = A * B^T + bias, output written in LSTM-transposed
// layout Gin2[t][wg][gate][jj][bb]  (wg=j>>4, jj=j&15; 4KB contiguous/WG/t)
// ---------------------------------------------------------------------------
__global__ __launch_bounds__(256) void gemm_f16(const _Float16* __restrict__ A,
                                                const _Float16* __restrict__ B,
                                                const float* __restrict__ bih,
                                                const float* __restrict__ bhh,
                                                float* __restrict__ Gin2,
                                                int M, int N, int K)
{
  __shared__ __align__(16) _Float16 As[128 * 32];
  __shared__ __align__(16) _Float16 Bs[128 * 32];
  const int tid  = threadIdx.x;
  const int lane = tid & 63;
  const int w    = tid >> 6;
  const int wm   = w >> 1, wn = w & 1;
  const int m0   = blockIdx.x * 128, n0 = blockIdx.y * 128;

  f32x4_t acc[4][4];
#pragma unroll
  for (int m = 0; m < 4; ++m)
#pragma unroll
    for (int n = 0; n < 4; ++n) acc[m][n] = (f32x4_t){0.f, 0.f, 0.f, 0.f};

  for (int k0 = 0; k0 < K; k0 += 32) {
#pragma unroll
    for (int r = 0; r < 2; ++r) {
      const int base = w * 2048 + r * 1024;
      const int off  = base + lane * 16;
      const int e    = off >> 1;
      const int row  = e >> 5;
      const int col  = e & 31;
      gl_lds16(A + (size_t)(m0 + row) * K + (k0 + col), (char*)As + base);
      gl_lds16(B + (size_t)(n0 + row) * K + (k0 + col), (char*)Bs + base);
    }
    __syncthreads();

    f16x8_t af[4], bfr[4];
    const int kb = (lane >> 4) * 16;
#pragma unroll
    for (int m = 0; m < 4; ++m)
      af[m] = *reinterpret_cast<const f16x8_t*>((const char*)As + (wm * 64 + m * 16 + (lane & 15)) * 64 + kb);
#pragma unroll
    for (int n = 0; n < 4; ++n)
      bfr[n] = *reinterpret_cast<const f16x8_t*>((const char*)Bs + (wn * 64 + n * 16 + (lane & 15)) * 64 + kb);
#pragma unroll
    for (int m = 0; m < 4; ++m)
#pragma unroll
      for (int n = 0; n < 4; ++n)
        acc[m][n] = __builtin_amdgcn_mfma_f32_16x16x32_f16(af[m], bfr[n], acc[m][n], 0, 0, 0);
    __syncthreads();
  }

#pragma unroll
  for (int m = 0; m < 4; ++m) {
#pragma unroll
    for (int n = 0; n < 4; ++n) {
      const int col  = n0 + wn * 64 + n * 16 + (lane & 15);
      const float bv = bih[col] + bhh[col];
      const int gate = col >> 11, j = col & 2047;
      const int wg = j >> 4, jj = j & 15;
#pragma unroll
      for (int r = 0; r < 4; ++r) {
        const int row = m0 + wm * 64 + m * 16 + (lane >> 4) * 4 + r;
        const int t = row >> 4, bb = row & 15;
        const size_t idx = ((((size_t)t * NWGL + wg) * 4 + gate) * 16 + jj) * 16 + bb;
        Gin2[idx] = acc[m][n][r] + bv;
      }
    }
  }
}

// ---------------------------------------------------------------------------
// K2: persistent LSTM. 128 WGs x 512 thr (8 waves), cooperative.
// WG owns 16 hidden units; wave wv owns K-slice [256wv,+256).
// W_hh fp16 frags register-resident. Fence-free IC h-exchange (round 8).
// ROUND 13: per-wave producer-group waits — wave wv polls only the 16
// producer WGs [16wv,16wv+16) of its K-slice (dataflow pipelining), no
// global rendezvous, no trailing syncthreads. 2 intra-WG barriers/step.
// ---------------------------------------------------------------------------
__global__ __launch_bounds__(512, 2) void lstm_persist(
    const _Float16* __restrict__ Whh,
    const float* __restrict__ Gin2,     // (256,128,4,16,16)
    const float* __restrict__ bih, const float* __restrict__ bhh,
    const float* __restrict__ c0,
    _Float16* __restrict__ Xh,          // 257 slots (16,2048) fp16
    bf16* __restrict__ XhHi, bf16* __restrict__ XhLo,  // 256 slots
    int* flags)                          // NWGL x 16 ints (64B stride)
{
  const int tid  = threadIdx.x;
  const int lane = tid & 63;
  const int wv   = tid >> 6;          // 0..7
  const int wg   = blockIdx.x;        // 0..127
  const int j0   = wg * 16;
  const int kw   = wv * 256;

  __shared__ float part[8][4][16][17];   // [wave][gate][batch][jj] padded

  // ---- register-resident W_hh fragments: tile g = gate, col nn = jj ----
  f16x8_t whh[4][8];
  {
    const int nn  = lane & 15;
    const int kfo = (lane >> 4) * 8;
#pragma unroll
    for (int g = 0; g < 4; ++g) {
      const size_t grow = (size_t)(g * H_DIM + j0 + nn) * 2048;
#pragma unroll
      for (int ks = 0; ks < 8; ++ks)
        whh[g][ks] = *reinterpret_cast<const f16x8_t*>(Whh + grow + kw + ks * 32 + kfo);
    }
  }

  // ---- per-thread cell state + bias (threads 0..255: bb=tid&15, jj=tid>>4) ----
  float c_reg = 0.f, cbr0 = 0.f, cbr1 = 0.f, cbr2 = 0.f, cbr3 = 0.f;
  if (tid < 256) {
    const int bb = tid & 15, jj = tid >> 4;
    const int j = j0 + jj;
    c_reg = c0[bb * H_DIM + j];
    cbr0 = bih[0 * H_DIM + j] + bhh[0 * H_DIM + j];
    cbr1 = bih[1 * H_DIM + j] + bhh[1 * H_DIM + j];
    cbr2 = bih[2 * H_DIM + j] + bhh[2 * H_DIM + j];
    cbr3 = bih[3 * H_DIM + j] + bhh[3 * H_DIM + j];
  }

  const size_t arow = (size_t)(lane & 15) * 2048 + kw + (lane >> 4) * 8;
  // this wave's producer flag (16 producers; 4 lanes share each flag)
  const int fidx = ((wv << 4) + (lane & 15)) << 4;

  for (int t = 0; t < L_DIM; ++t) {
    // wait for THIS WAVE's h-slice producers only (dataflow, no global bar)
    if (t > 0) {
      while (true) {
        const int v = __hip_atomic_load(&flags[fidx], __ATOMIC_RELAXED,
                                        __HIP_MEMORY_SCOPE_AGENT);
        if (__all(v >= t)) break;
        __builtin_amdgcn_s_sleep(1);
      }
    }

    // Gin2 for this step: 4 coalesced 1KB blocks per WG
    float gin0 = 0.f, gin1 = 0.f, gin2v = 0.f, gin3 = 0.f;
    if (tid < 256) {
      const float* gbase = Gin2 + ((size_t)t * NWGL + wg) * 1024;
      gin0  = gbase[0 * 256 + tid];
      gin1  = gbase[1 * 256 + tid];
      gin2v = gbase[2 * 256 + tid];
      gin3  = gbase[3 * 256 + tid];
    }

    // h fragments from Xh slot t — coherent IC reads (bypass L1/L2)
    const size_t hoff = (size_t)t * 32768 + arow;
    f16x8_t hf[8];
#pragma unroll
    for (int ks = 0; ks < 8; ++ks)
      hf[ks] = load_f16x8_sc(Xh + hoff + ks * 32);
    asm volatile("s_waitcnt vmcnt(0)" ::: "memory");
    __builtin_amdgcn_sched_barrier(0);   // rule #18: keep MFMAs below the wait

    f32x4_t acc[4];
#pragma unroll
    for (int g = 0; g < 4; ++g) acc[g] = (f32x4_t){0.f, 0.f, 0.f, 0.f};
#pragma unroll
    for (int ks = 0; ks < 8; ++ks) {
#pragma unroll
      for (int g = 0; g < 4; ++g)
        acc[g] = __builtin_amdgcn_mfma_f32_16x16x32_f16(hf[ks], whh[g][ks], acc[g], 0, 0, 0);
    }
#pragma unroll
    for (int g = 0; g < 4; ++g)
#pragma unroll
      for (int r = 0; r < 4; ++r)
        part[wv][g][(lane >> 4) * 4 + r][lane & 15] = acc[g][r];
    __syncthreads();                    // 1: all part[] written

    if (tid < 256) {
      const int bb = tid & 15, jj = tid >> 4;
      float g4[4] = {gin0, gin1, gin2v, gin3};
      const float cb4[4] = {cbr0, cbr1, cbr2, cbr3};
#pragma unroll
      for (int g = 0; g < 4; ++g) {
        float s = 0.f;
#pragma unroll
        for (int v = 0; v < 8; ++v) s += part[v][g][bb][jj];
        g4[g] += s + cb4[g];
      }
      const float i_ = sigmoidf_(g4[0]);
      const float f_ = sigmoidf_(g4[1]);
      const float g_ = tanhf(g4[2]);
      const float o_ = sigmoidf_(g4[3]);
      c_reg = f_ * c_reg + i_ * g_;
      const float h = o_ * tanhf(c_reg);
      const int bj = bb * 2048 + j0 + jj;
      const _Float16 hF = (_Float16)h;
      const bf16 hhv = f2b(h);
      const bf16 hlv = f2b(h - (float)hhv);
      const size_t xi = ((size_t)t * 16 + bb) * 2048 + j0 + jj;
      store_short_sc(Xh + (size_t)(t + 1) * 32768 + bj,
                     (unsigned int)__builtin_bit_cast(unsigned short, hF));
      store_short_sc(XhHi + xi,
                     (unsigned int)__builtin_bit_cast(unsigned short, hhv));
      store_short_sc(XhLo + xi,
                     (unsigned int)__builtin_bit_cast(unsigned short, hlv));
    }
    // drain write-through stores to IC before publishing arrival
    asm volatile("s_waitcnt vmcnt(0)" ::: "memory");
    __syncthreads();                    // 2: all waves' stores drained

    if (t < L_DIM - 1 && tid == 0)
      __hip_atomic_store(&flags[wg << 4], t + 1, __ATOMIC_RELAXED,
                         __HIP_MEMORY_SCOPE_AGENT);
  }
}

// ---------------------------------------------------------------------------
// K3: split-bf16 (hi+lo) NT GEMM — ~fp32 via 3 products (FWM projections).
// MODE 1: C = acc + bias ; MODE 2: C = tanh(acc + bias)
// ---------------------------------------------------------------------------
template <int MODE>
__global__ __launch_bounds__(256) void gemm_nt3(const bf16* __restrict__ A_hi,
                                                const bf16* __restrict__ A_lo,
                                                const bf16* __restrict__ B_hi,
                                                const bf16* __restrict__ B_lo,
                                                const float* __restrict__ bias,
                                                float* __restrict__ C,
                                                int M, int N, int K)
{
  __shared__ __align__(16) bf16 As[2][128 * 32];
  __shared__ __align__(16) bf16 Bs[2][128 * 32];
  const int tid  = threadIdx.x;
  const int lane = tid & 63;
  const int w    = tid >> 6;
  const int wm   = w >> 1, wn = w & 1;
  const int m0   = blockIdx.x * 128, n0 = blockIdx.y * 128;

  f32x4_t acc[4][4];
#pragma unroll
  for (int m = 0; m < 4; ++m)
#pragma unroll
    for (int n = 0; n < 4; ++n) acc[m][n] = (f32x4_t){0.f, 0.f, 0.f, 0.f};

  for (int k0 = 0; k0 < K; k0 += 32) {
#pragma unroll
    for (int r = 0; r < 2; ++r) {
      const int base = w * 2048 + r * 1024;
      const int off  = base + lane * 16;
      const int e    = off >> 1;
      const int row  = e >> 5;
      const int col  = e & 31;
      const size_t gA = (size_t)(m0 + row) * K + (k0 + col);
      const size_t gB = (size_t)(n0 + row) * K + (k0 + col);
      gl_lds16(A_hi + gA, (char*)As[0] + base);
      gl_lds16(A_lo + gA, (char*)As[1] + base);
      gl_lds16(B_hi + gB, (char*)Bs[0] + base);
      gl_lds16(B_lo + gB, (char*)Bs[1] + base);
    }
    __syncthreads();

    bf16x8_t afh[4], afl[4], bfh[4], bfl[4];
    const int kb = (lane >> 4) * 16;
#pragma unroll
    for (int m = 0; m < 4; ++m) {
      const int ro = (wm * 64 + m * 16 + (lane & 15)) * 64 + kb;
      afh[m] = *reinterpret_cast<const bf16x8_t*>((const char*)As[0] + ro);
      afl[m] = *reinterpret_cast<const bf16x8_t*>((const char*)As[1] + ro);
    }
#pragma unroll
    for (int n = 0; n < 4; ++n) {
      const int ro = (wn * 64 + n * 16 + (lane & 15)) * 64 + kb;
      bfh[n] = *reinterpret_cast<const bf16x8_t*>((const char*)Bs[0] + ro);
      bfl[n] = *reinterpret_cast<const bf16x8_t*>((const char*)Bs[1] + ro);
    }
#pragma unroll
    for (int m = 0; m < 4; ++m)
#pragma unroll
      for (int n = 0; n < 4; ++n) {
        acc[m][n] = __builtin_amdgcn_mfma_f32_16x16x32_bf16(afh[m], bfh[n], acc[m][n], 0, 0, 0);
        acc[m][n] = __builtin_amdgcn_mfma_f32_16x16x32_bf16(afh[m], bfl[n], acc[m][n], 0, 0, 0);
        acc[m][n] = __builtin_amdgcn_mfma_f32_16x16x32_bf16(afl[m], bfh[n], acc[m][n], 0, 0, 0);
      }
    __syncthreads();
  }

#pragma unroll
  for (int m = 0; m < 4; ++m) {
#pragma unroll
    for (int n = 0; n < 4; ++n) {
      const int col = n0 + wn * 64 + n * 16 + (lane & 15);
      const float bv = bias[col];
#pragma unroll
      for (int r = 0; r < 4; ++r) {
        const int row = m0 + wm * 64 + m * 16 + (lane >> 4) * 4 + r;
        float v = acc[m][n][r] + bv;
        if (MODE == 2) v = tanhf(v);
        C[(size_t)row * N + col] = v;
      }
    }
  }
}

// ---------------------------------------------------------------------------
// K4a: FWM scan D1 (F-recurrence). 16 WGs x 512 thr (8 waves). Parity
// double-buffered LDS staging -> 2 barriers/step. Redundant per-wave norm
// (no barrier). G_jit -> global (fire-and-forget; q-chain in K4b).
// ---------------------------------------------------------------------------
__global__ __launch_bounds__(512, 2) void fwm_scan(const float* __restrict__ Wall,   // (4096,128)
                                                   const float* __restrict__ RVall,  // (4096,128)
                                                   const float* __restrict__ F0,     // (16,1024,32)
                                                   float* __restrict__ Gbuf)         // (4096,3,32,32)
{
  const int b    = blockIdx.x;
  const int tid  = threadIdx.x;
  const int lane = tid & 63;
  const int wv   = tid >> 6;          // 0..7
  const int si    = lane >> 1;        // s-index for this lane's k-range
  const int rbase = 16 * (lane & 1);  // r-index base
  const int tl    = lane & 31;        // t-index for redundant norm phase

  __shared__ float s_s[2][32], s_r[2][32], s_tv[2][32], s_bb[2];
  __shared__ float s_rv[2][128];
  __shared__ float s_v[32];
  __shared__ float s_red[8];

  float F[16][4];
#pragma unroll
  for (int i = 0; i < 16; ++i)
#pragma unroll
    for (int j = 0; j < 4; ++j)
      F[i][j] = F0[((size_t)b * 1024 + (16 * lane + i)) * 32 + 4 * wv + j];

  // initial ||F||^2 (one-time full reduce); N maintained redundantly per wave
  float N = 0.f;
  {
    float loc = 0.f;
#pragma unroll
    for (int i = 0; i < 16; ++i)
#pragma unroll
      for (int j = 0; j < 4; ++j) loc += F[i][j] * F[i][j];
#pragma unroll
    for (int m = 1; m < 64; m <<= 1) loc += __shfl_xor(loc, m);
    if (lane == 0) s_red[wv] = loc;
    __syncthreads();
#pragma unroll
    for (int k = 0; k < 8; ++k) N += s_red[k];
  }

  // prefetch t=0
  float wpre = 0.f, rvpre = 0.f;
  if (tid < 97) wpre = Wall[(size_t)b * 128 + tid];
  if (tid >= 128 && tid < 256) rvpre = RVall[(size_t)b * 128 + tid - 128];

  for (int t = 0; t < 256; ++t) {
    const int par = t & 1;
    // stage parity-p buffers (prior readers of this parity finished at t-2;
    // separated by both barriers of t-1)
    if (tid < 32)       s_s[par][tid]       = tanhf(wpre);
    else if (tid < 64)  s_r[par][tid - 32]  = tanhf(wpre);
    else if (tid < 96)  s_tv[par][tid - 64] = tanhf(wpre);
    else if (tid == 96) s_bb[par]           = sigmoidf_(wpre + 1.f);
    else if (tid >= 128 && tid < 256) s_rv[par][tid - 128] = rvpre;
    __syncthreads();                  // 1: staging visible

    // prefetch t+1 (overlaps compute)
    if (t < 255) {
      const float* wrow2  = Wall  + (size_t)((t + 1) * 16 + b) * 128;
      const float* rvrow2 = RVall + (size_t)((t + 1) * 16 + b) * 128;
      if (tid < 97) wpre = wrow2[tid];
      if (tid >= 128 && tid < 256) rvpre = rvrow2[tid - 128];
    }

    const float sv = s_s[par][si];
    float sr[16];
#pragma unroll
    for (int i = 0; i < 16; ++i) sr[i] = sv * s_r[par][rbase + i];

    // v_t = sum_k sr[k] F[k,t] (4 wave-local t-columns)
    float vv4[4];
#pragma unroll
    for (int j = 0; j < 4; ++j) {
      float pp = 0.f;
#pragma unroll
      for (int i = 0; i < 16; ++i) pp += sr[i] * F[i][j];
#pragma unroll
      for (int m = 1; m < 64; m <<= 1) pp += __shfl_xor(pp, m);
      vv4[j] = pp;
    }
    if (lane == 0) {
#pragma unroll
      for (int j = 0; j < 4; ++j) s_v[4 * wv + j] = vv4[j];
    }
    __syncthreads();                  // 2: all v ready

    // redundant norm/u in EVERY wave — no barrier, no wave-0 tail
    const float vt  = s_v[tl];
    const float ut  = s_bb[par] * (s_tv[par][tl] - vt);
    const float sl  = s_s[par][tl];
    const float rl  = s_r[par][tl];
    float uv = ut * vt, uu = ut * ut, ss = sl * sl, rr = rl * rl;
#pragma unroll
    for (int m = 1; m < 32; m <<= 1) {
      uv += __shfl_xor(uv, m);
      uu += __shfl_xor(uu, m);
      ss += __shfl_xor(ss, m);
      rr += __shfl_xor(rr, m);
    }
    const float Np  = N + 2.f * uv + ss * rr * uu;
    const float n_  = sqrtf(Np);
    const float inv = 1.f / (fmaxf(n_ - 1.f, 0.f) + 1.f);
    N = Np * inv * inv;

    // u for own cols via in-wave broadcast (lane 4wv+j holds t=4wv+j)
    float uw[4];
#pragma unroll
    for (int j = 0; j < 4; ++j) uw[j] = __shfl(ut, 4 * wv + j);
#pragma unroll
    for (int i = 0; i < 16; ++i)
#pragma unroll
      for (int j = 0; j < 4; ++j)
        F[i][j] = (F[i][j] + sr[i] * uw[j]) * inv;

    // G_jit[i,t] = sum_j rj[j] F[32i+j,t] -> GLOBAL (fire-and-forget)
    float* gout = Gbuf + ((size_t)(t * 16 + b) * 3) * 1024;
#pragma unroll
    for (int jit = 0; jit < 3; ++jit) {
      float rjv[16];
#pragma unroll
      for (int i = 0; i < 16; ++i) rjv[i] = s_rv[par][32 + 32 * jit + rbase + i];
      f32x4_t gv;
#pragma unroll
      for (int j = 0; j < 4; ++j) {
        float g = 0.f;
#pragma unroll
        for (int i = 0; i < 16; ++i) g += rjv[i] * F[i][j];
        g += __shfl_xor(g, 1);        // combine the two j-halves of row i
        gv[j] = g;
      }
      if ((lane & 1) == 0)
        *reinterpret_cast<f32x4_t*>(gout + jit * 1024 + (lane >> 1) * 32 + 4 * wv) = gv;
    }
    // no trailing barrier: next step stages the OTHER parity; s_v write for
    // t+1 happens after barrier 1 of t+1, read of s_v here precedes it.
  }
}

// ---------------------------------------------------------------------------
// K4b: FWM q-readout D2 — 4096 independent (t,b) chains, one wave each.
// ---------------------------------------------------------------------------
__global__ __launch_bounds__(256) void fwm_qread(const float* __restrict__ Gbuf,   // (4096,3,32,32)
                                                 const float* __restrict__ RVall,  // (4096,128)
                                                 float* __restrict__ QS)           // (4096,32)
{
  const int pair = blockIdx.x * 4 + (threadIdx.x >> 6);  // t*16+b
  const int lane = threadIdx.x & 63;
  const int tq    = lane & 31;
  const int ihalf = (lane >> 5) * 16;

  const float* G  = Gbuf + (size_t)pair * 3 * 1024;
  float q = RVall[(size_t)pair * 128 + tq];
#pragma unroll 1
  for (int jit = 0; jit < 3; ++jit) {
    float c = 0.f;
#pragma unroll
    for (int i = 0; i < 16; ++i) {
      const float qi = __shfl(q, ihalf + i);   // lanes 0..31 hold q_t
      c += qi * G[jit * 1024 + (ihalf + i) * 32 + tq];
    }
    c += __shfl_xor(c, 32);           // both halves now hold full c_t
    float mval = c;
#pragma unroll
    for (int m = 1; m < 32; m <<= 1) mval += __shfl_xor(mval, m);
    mval *= (1.f / 32.f);
    const float dl = c - mval;
    float var = dl * dl;
#pragma unroll
    for (int m = 1; m < 32; m <<= 1) var += __shfl_xor(var, m);
    var *= (1.f / 32.f);
    q = dl * rsqrtf(var + 1e-5f);
  }
  if (lane < 32) QS[(size_t)pair * 32 + lane] = q;
}

// ---------------------------------------------------------------------------
// K5: out = (XhHi+XhLo) + QS @ Wlin^T + blin
// ---------------------------------------------------------------------------
__global__ __launch_bounds__(256) void out_kernel(const bf16* __restrict__ Xh1Hi,
                                                  const bf16* __restrict__ Xh1Lo,
                                                  const float* __restrict__ QS,
                                                  const float* __restrict__ Wlin,  // (2048,32)
                                                  const float* __restrict__ blin,
                                                  float* __restrict__ out)
{
  __shared__ float qs[32];
  const int row = blockIdx.x;
  if (threadIdx.x < 32) qs[threadIdx.x] = QS[(size_t)row * 32 + threadIdx.x];
  __syncthreads();
  for (int h = threadIdx.x; h < H_DIM; h += 256) {
    const size_t xi = (size_t)row * H_DIM + h;
    float acc = (float)Xh1Hi[xi] + (float)Xh1Lo[xi] + blin[h];
    const float* wr = Wlin + (size_t)h * 32;
#pragma unroll
    for (int t2 = 0; t2 < 32; ++t2) acc += qs[t2] * wr[t2];
    out[xi] = acc;
  }
}

// ---------------------------------------------------------------------------
// Workspace (~237 MB), lifetime-aliased (unchanged layout from round 11).
// ---------------------------------------------------------------------------
extern "C" void kernel_launch(void* const* d_in, const int* in_sizes, int n_in,
                              void* d_out, int out_size, void* d_ws, size_t ws_size,
                              hipStream_t stream)
{
  (void)in_sizes; (void)n_in; (void)out_size; (void)ws_size;
  const float* inp  = (const float*)d_in[0];
  const float* h0   = (const float*)d_in[1];
  const float* c0   = (const float*)d_in[2];
  const float* F0   = (const float*)d_in[3];
  const float* Wih  = (const float*)d_in[4];
  const float* Whh  = (const float*)d_in[5];
  const float* bih  = (const float*)d_in[6];
  const float* bhh  = (const float*)d_in[7];
  const float* Www  = (const float*)d_in[8];
  const float* Wwb  = (const float*)d_in[9];
  const float* Wrw  = (const float*)d_in[10];
  const float* Wrb  = (const float*)d_in[11];
  const float* Wlin = (const float*)d_in[12];
  const float* blin = (const float*)d_in[13];
  float* out = (float*)d_out;

  char* p = (char*)d_ws;
  auto alloc = [&](size_t bytes) {
    char* r = p;
    p += (bytes + 255) & ~(size_t)255;
    return r;
  };
  _Float16* Whh_f = (_Float16*)alloc(16777216ull * 2);   // 33.5 MB
  _Float16* Wih_f = (_Float16*)alloc(16777216ull * 2);   // 33.5 MB
  _Float16* inp_f = (_Float16*)alloc(8388608ull * 2);    // 16.8 MB
  float*    Gin   = (float*)alloc(33554432ull * 4);      // 134 MB (Gin2 layout)
  _Float16* Xh    = (_Float16*)alloc(257ull * 32768 * 2);// 16.9 MB
  bf16*  Wq_hi  = (bf16*)alloc(262144ull * 2);
  bf16*  Wq_lo  = (bf16*)alloc(262144ull * 2);
  bf16*  Wr_hi  = (bf16*)alloc(262144ull * 2);
  bf16*  Wr_lo  = (bf16*)alloc(262144ull * 2);
  float* wbpad  = (float*)alloc(128ull * 4);
  int*   flags  = (int*)alloc(NWGL * 64);                // 64B line per WG
  // aliases (strictly later lifetimes):
  bf16*  XhHi  = (bf16*)inp_f;          // written by persist after Gin GEMM consumed inp_f
  bf16*  XhLo  = (bf16*)Wih_f;          // written after Wih consumed
  float* Wall  = Gin;                   // 2 MB, written after persist consumed Gin
  float* RVall = Gin + 524288;          // 2 MB
  float* QS    = Gin + 1048576;         // 0.5 MB
  float* Gbuf  = Gin + 2097152;         // 50.3 MB (4096 x 3 x 32 x 32 f32)

  prep_kernel<<<2048, 256, 0, stream>>>(Wih, Whh, inp, Www, Wwb, Wrw, h0,
                                        Wih_f, Whh_f, inp_f,
                                        Wq_hi, Wq_lo, Wr_hi, Wr_lo, wbpad, Xh);

  // Phase A: Gin2 = x @ W_ih^T + bias, in LSTM-transposed layout
  gemm_f16<<<dim3(32, 64), 256, 0, stream>>>(inp_f, Wih_f, bih, bhh, Gin,
                                             MROWS, G4, 2048);

  // Phase B: persistent cooperative LSTM (128 WGs, per-wave producer waits)
  hipMemsetAsync(flags, 0, NWGL * 64, stream);
  {
    void* kargs[] = {
      (void*)&Whh_f, (void*)&Gin, (void*)&bih, (void*)&bhh, (void*)&c0,
      (void*)&Xh, (void*)&XhHi, (void*)&XhLo, (void*)&flags
    };
    hipLaunchCooperativeKernel((const void*)lstm_persist, dim3(NWGL), dim3(512),
                               kargs, 0, stream);
  }

  // Phase C: FWM projections (~fp32 via split-bf16)
  gemm_nt3<1><<<dim3(32, 1), 256, 0, stream>>>(XhHi, XhLo, Wq_hi, Wq_lo, wbpad,
                                               Wall, MROWS, 128, 2048);
  gemm_nt3<2><<<dim3(32, 1), 256, 0, stream>>>(XhHi, XhLo, Wr_hi, Wr_lo, Wrb,
                                               RVall, MROWS, 128, 2048);

  // Phase D1: FWM F-recurrence scan (8 waves, 2 barriers/step, G -> global)
  fwm_scan<<<16, 512, 0, stream>>>(Wall, RVall, F0, Gbuf);

  // Phase D2: q-readout — 4096 independent chains, massively parallel
  fwm_qread<<<1024, 256, 0, stream>>>(Gbuf, RVall, QS);

  // Phase E: out = x + QS @ Wlin^T + blin
  out_kernel<<<4096, 256, 0, stream>>>(XhHi, XhLo, QS, Wlin, blin, out);
}

// Round 14
// 1905.299 us; speedup vs baseline: 1.8822x; 1.3375x over previous
//
#include <hip/hip_runtime.h>
#include <hip/hip_bf16.h>
#include <cstdint>
#include <cstddef>

// Problem constants: L=256, B=16, I=2048, H=2048, S=R=T=32
#define L_DIM 256
#define B_DIM 16
#define I_DIM 2048
#define H_DIM 2048
#define G4    8192
#define MROWS 4096
#define NWGL  128            // LSTM workgroups (each owns 16 hidden units)
#define NPRJ  16             // projection workgroups (16 output cols each)
#define NSCN  16             // scan workgroups (one per batch)

typedef __hip_bfloat16 bf16;
typedef __bf16 bf16x8_t __attribute__((ext_vector_type(8)));
typedef _Float16 f16x8_t __attribute__((ext_vector_type(8)));
typedef float f32x4_t   __attribute__((ext_vector_type(4)));

__device__ __forceinline__ bf16 f2b(float f) { return __float2bfloat16(f); }

__device__ __forceinline__ void gl_lds16(const void* g, void* l) {
  __builtin_amdgcn_global_load_lds(
      (const __attribute__((address_space(1))) unsigned int*)g,
      (__attribute__((address_space(3))) unsigned int*)l, 16, 0, 0);
}

__device__ __forceinline__ float sigmoidf_(float x) { return 1.f / (1.f + expf(-x)); }

// Coherent (IC-through) access helpers — proven fence-free protocol (r8).
__device__ __forceinline__ f16x8_t load_f16x8_sc(const _Float16* p) {
  f16x8_t r;
  asm volatile("global_load_dwordx4 %0, %1, off sc0 sc1" : "=v"(r) : "v"(p));
  return r;
}
__device__ __forceinline__ bf16x8_t load_bf16x8_sc(const bf16* p) {
  bf16x8_t r;
  asm volatile("global_load_dwordx4 %0, %1, off sc0 sc1" : "=v"(r) : "v"(p));
  return r;
}
__device__ __forceinline__ float load_f32_sc(const float* p) {
  float r;
  asm volatile("global_load_dword %0, %1, off sc0 sc1" : "=v"(r) : "v"(p));
  return r;
}
__device__ __forceinline__ void store_short_sc(void* p, unsigned int v) {
  asm volatile("global_store_short %0, %1, off sc0 sc1" :: "v"(p), "v"(v) : "memory");
}
__device__ __forceinline__ void store_f32_sc(void* p, float v) {
  asm volatile("global_store_dword %0, %1, off sc0 sc1" :: "v"(p), "v"(v) : "memory");
}

// ---------------------------------------------------------------------------
// K0: prep — fp16 casts (LSTM path), bf16 hi/lo (FWM weights), h0 fp16
// ---------------------------------------------------------------------------
__global__ void prep_kernel(const float* __restrict__ Wih, const float* __restrict__ Whh,
                            const float* __restrict__ inp, const float* __restrict__ Www,
                            const float* __restrict__ Wwb, const float* __restrict__ Wrw,
                            const float* __restrict__ h0,
                            _Float16* __restrict__ Wih_f, _Float16* __restrict__ Whh_f,
                            _Float16* __restrict__ inp_f,
                            bf16* __restrict__ Wq_hi, bf16* __restrict__ Wq_lo,
                            bf16* __restrict__ Wr_hi, bf16* __restrict__ Wr_lo,
                            float* __restrict__ wbpad,
                            _Float16* __restrict__ Xh0)
{
  size_t idx0 = (size_t)blockIdx.x * blockDim.x + threadIdx.x;
  size_t stride = (size_t)gridDim.x * blockDim.x;
  for (size_t i = idx0; i < 16777216ull; i += stride) {
    Wih_f[i] = (_Float16)Wih[i];
    Whh_f[i] = (_Float16)Whh[i];
  }
  for (size_t i = idx0; i < 8388608ull; i += stride) inp_f[i] = (_Float16)inp[i];
  for (size_t i = idx0; i < 262144ull; i += stride) {
    size_t r = i >> 11;
    float q = (r < 97) ? Www[i] : 0.f;
    bf16 qh = f2b(q);
    Wq_hi[i] = qh;
    Wq_lo[i] = f2b(q - (float)qh);
    float rr = Wrw[i];
    bf16 rh = f2b(rr);
    Wr_hi[i] = rh;
    Wr_lo[i] = f2b(rr - (float)rh);
  }
  for (size_t i = idx0; i < 128ull; i += stride) wbpad[i] = (i < 97) ? Wwb[i] : 0.f;
  for (size_t i = idx0; i < 32768ull; i += stride) Xh0[i] = (_Float16)h0[i];
}

// ---------------------------------------------------------------------------
// K1: fp16 NT GEMM  C = A * B^T + bias, output fp16 in LSTM-transposed
// layout Gin2[t][wg][gate][jj][bb]
// ---------------------------------------------------------------------------
__global__ __launch_bounds__(256) void gemm_f16(const _Float16* __restrict__ A,
                                                const _Float16* __restrict__ B,
                                                const float* __restrict__ bih,
                                                const float* __restrict__ bhh,
                                                _Float16* __restrict__ Gin2,
                                                int M, int N, int K)
{
  __shared__ __align__(16) _Float16 As[128 * 32];
  __shared__ __align__(16) _Float16 Bs[128 * 32];
  const int tid  = threadIdx.x;
  const int lane = tid & 63;
  const int w    = tid >> 6;
  const int wm   = w >> 1, wn = w & 1;
  const int m0   = blockIdx.x * 128, n0 = blockIdx.y * 128;

  f32x4_t acc[4][4];
#pragma unroll
  for (int m = 0; m < 4; ++m)
#pragma unroll
    for (int n = 0; n < 4; ++n) acc[m][n] = (f32x4_t){0.f, 0.f, 0.f, 0.f};

  for (int k0 = 0; k0 < K; k0 += 32) {
#pragma unroll
    for (int r = 0; r < 2; ++r) {
      const int base = w * 2048 + r * 1024;
      const int off  = base + lane * 16;
      const int e    = off >> 1;
      const int row  = e >> 5;
      const int col  = e & 31;
      gl_lds16(A + (size_t)(m0 + row) * K + (k0 + col), (char*)As + base);
      gl_lds16(B + (size_t)(n0 + row) * K + (k0 + col), (char*)Bs + base);
    }
    __syncthreads();

    f16x8_t af[4], bfr[4];
    const int kb = (lane >> 4) * 16;
#pragma unroll
    for (int m = 0; m < 4; ++m)
      af[m] = *reinterpret_cast<const f16x8_t*>((const char*)As + (wm * 64 + m * 16 + (lane & 15)) * 64 + kb);
#pragma unroll
    for (int n = 0; n < 4; ++n)
      bfr[n] = *reinterpret_cast<const f16x8_t*>((const char*)Bs + (wn * 64 + n * 16 + (lane & 15)) * 64 + kb);
#pragma unroll
    for (int m = 0; m < 4; ++m)
#pragma unroll
      for (int n = 0; n < 4; ++n)
        acc[m][n] = __builtin_amdgcn_mfma_f32_16x16x32_f16(af[m], bfr[n], acc[m][n], 0, 0, 0);
    __syncthreads();
  }

#pragma unroll
  for (int m = 0; m < 4; ++m) {
#pragma unroll
    for (int n = 0; n < 4; ++n) {
      const int col  = n0 + wn * 64 + n * 16 + (lane & 15);
      const float bv = bih[col] + bhh[col];
      const int gate = col >> 11, j = col & 2047;
      const int wg = j >> 4, jj = j & 15;
#pragma unroll
      for (int r = 0; r < 4; ++r) {
        const int row = m0 + wm * 64 + m * 16 + (lane >> 4) * 4 + r;
        const int t = row >> 4, bb = row & 15;
        const size_t idx = ((((size_t)t * NWGL + wg) * 4 + gate) * 16 + jj) * 16 + bb;
        Gin2[idx] = (_Float16)(acc[m][n][r] + bv);
      }
    }
  }
}

// ---------------------------------------------------------------------------
// K2: FUSED persistent RNN (160 WGs x 512 thr, cooperative):
//   WG 0..127   : LSTM step pipeline (round-13 structure, always publishes)
//   WG 128..143 : projection — 16 output cols each of stacked [Wq;Wr],
//                 polls lstm flags, MFMA on x(t) hi/lo, write-through rows
//   WG 144..159 : FWM F-scan (one per batch), polls proj flags, G -> global
// All cross-WG hand-offs use the proven sc0/sc1 + vmcnt(0) + flag protocol.
// ---------------------------------------------------------------------------
__global__ __launch_bounds__(512, 2) void fused_rnn(
    const _Float16* __restrict__ Whh,
    const _Float16* __restrict__ Gin2,   // (256,128,4,16,16) fp16
    const float* __restrict__ bih, const float* __restrict__ bhh,
    const float* __restrict__ c0,
    const bf16* __restrict__ Wq_hi, const bf16* __restrict__ Wq_lo,
    const bf16* __restrict__ Wr_hi, const bf16* __restrict__ Wr_lo,
    const float* __restrict__ wbpad, const float* __restrict__ Wrb,
    const float* __restrict__ F0,
    _Float16* __restrict__ Xh,
    bf16* __restrict__ XhHi, bf16* __restrict__ XhLo,
    float* __restrict__ Wall, float* __restrict__ RVall,
    float* __restrict__ Gbuf,
    int* lflags, int* pflags)
{
  __shared__ float part[8][4][16][17];          // lstm reduce; proj uses [][0]
  __shared__ float s_s[32], s_r[32], s_tv[32], s_bb;
  __shared__ float s_rv[128];
  __shared__ float s_v[32];
  __shared__ float s_red[8];

  const int wgid = blockIdx.x;
  const int tid  = threadIdx.x;
  const int lane = tid & 63;
  const int wv   = tid >> 6;          // 0..7

  if (wgid < NWGL) {
    // ===================== LSTM =====================
    const int wg = wgid;
    const int j0 = wg * 16;
    const int kw = wv * 256;

    f16x8_t whh[4][8];
    {
      const int nn  = lane & 15;
      const int kfo = (lane >> 4) * 8;
#pragma unroll
      for (int g = 0; g < 4; ++g) {
        const size_t grow = (size_t)(g * H_DIM + j0 + nn) * 2048;
#pragma unroll
        for (int ks = 0; ks < 8; ++ks)
          whh[g][ks] = *reinterpret_cast<const f16x8_t*>(Whh + grow + kw + ks * 32 + kfo);
      }
    }

    float c_reg = 0.f, cbr0 = 0.f, cbr1 = 0.f, cbr2 = 0.f, cbr3 = 0.f;
    if (tid < 256) {
      const int bb = tid & 15, jj = tid >> 4;
      const int j = j0 + jj;
      c_reg = c0[bb * H_DIM + j];
      cbr0 = bih[0 * H_DIM + j] + bhh[0 * H_DIM + j];
      cbr1 = bih[1 * H_DIM + j] + bhh[1 * H_DIM + j];
      cbr2 = bih[2 * H_DIM + j] + bhh[2 * H_DIM + j];
      cbr3 = bih[3 * H_DIM + j] + bhh[3 * H_DIM + j];
    }

    const size_t arow = (size_t)(lane & 15) * 2048 + kw + (lane >> 4) * 8;
    const int fidx = ((wv << 4) + (lane & 15)) << 4;   // this wave's producers

    for (int t = 0; t < L_DIM; ++t) {
      if (t > 0) {
        while (true) {
          const int v = __hip_atomic_load(&lflags[fidx], __ATOMIC_RELAXED,
                                          __HIP_MEMORY_SCOPE_AGENT);
          if (__all(v >= t)) break;
          __builtin_amdgcn_s_sleep(1);
        }
      }

      float gin0 = 0.f, gin1 = 0.f, gin2v = 0.f, gin3 = 0.f;
      if (tid < 256) {
        const _Float16* gbase = Gin2 + ((size_t)t * NWGL + wg) * 1024;
        gin0  = (float)gbase[0 * 256 + tid];
        gin1  = (float)gbase[1 * 256 + tid];
        gin2v = (float)gbase[2 * 256 + tid];
        gin3  = (float)gbase[3 * 256 + tid];
      }

      const size_t hoff = (size_t)t * 32768 + arow;
      f16x8_t hf[8];
#pragma unroll
      for (int ks = 0; ks < 8; ++ks)
        hf[ks] = load_f16x8_sc(Xh + hoff + ks * 32);
      asm volatile("s_waitcnt vmcnt(0)" ::: "memory");
      __builtin_amdgcn_sched_barrier(0);

      f32x4_t acc[4];
#pragma unroll
      for (int g = 0; g < 4; ++g) acc[g] = (f32x4_t){0.f, 0.f, 0.f, 0.f};
#pragma unroll
      for (int ks = 0; ks < 8; ++ks) {
#pragma unroll
        for (int g = 0; g < 4; ++g)
          acc[g] = __builtin_amdgcn_mfma_f32_16x16x32_f16(hf[ks], whh[g][ks], acc[g], 0, 0, 0);
      }
#pragma unroll
      for (int g = 0; g < 4; ++g)
#pragma unroll
        for (int r = 0; r < 4; ++r)
          part[wv][g][(lane >> 4) * 4 + r][lane & 15] = acc[g][r];
      __syncthreads();

      if (tid < 256) {
        const int bb = tid & 15, jj = tid >> 4;
        float g4[4] = {gin0, gin1, gin2v, gin3};
        const float cb4[4] = {cbr0, cbr1, cbr2, cbr3};
#pragma unroll
        for (int g = 0; g < 4; ++g) {
          float s = 0.f;
#pragma unroll
          for (int v = 0; v < 8; ++v) s += part[v][g][bb][jj];
          g4[g] += s + cb4[g];
        }
        const float i_ = sigmoidf_(g4[0]);
        const float f_ = sigmoidf_(g4[1]);
        const float g_ = tanhf(g4[2]);
        const float o_ = sigmoidf_(g4[3]);
        c_reg = f_ * c_reg + i_ * g_;
        const float h = o_ * tanhf(c_reg);
        const int bj = bb * 2048 + j0 + jj;
        const _Float16 hF = (_Float16)h;
        const bf16 hhv = f2b(h);
        const bf16 hlv = f2b(h - (float)hhv);
        const size_t xi = ((size_t)t * 16 + bb) * 2048 + j0 + jj;
        store_short_sc(Xh + (size_t)(t + 1) * 32768 + bj,
                       (unsigned int)__builtin_bit_cast(unsigned short, hF));
        store_short_sc(XhHi + xi,
                       (unsigned int)__builtin_bit_cast(unsigned short, hhv));
        store_short_sc(XhLo + xi,
                       (unsigned int)__builtin_bit_cast(unsigned short, hlv));
      }
      asm volatile("s_waitcnt vmcnt(0)" ::: "memory");
      __syncthreads();

      if (tid == 0)
        __hip_atomic_store(&lflags[wg << 4], t + 1, __ATOMIC_RELAXED,
                           __HIP_MEMORY_SCOPE_AGENT);
    }

  } else if (wgid < NWGL + NPRJ) {
    // ===================== PROJECTION =====================
    const int p   = wgid - NWGL;     // 0..15 ; cols [16p,16p+16) of [Wq;Wr]
    const int kw  = wv * 256;
    const int nn  = lane & 15;
    const int kfo = (lane >> 4) * 8;

    // register-resident B fragments (hi/lo)
    bf16x8_t wbh[8], wbl[8];
    {
      const bf16* Bh = (p < 8) ? Wq_hi : Wr_hi;
      const bf16* Bl = (p < 8) ? Wq_lo : Wr_lo;
      const int brow = (p < 8) ? (p * 16 + nn) : ((p - 8) * 16 + nn);
#pragma unroll
      for (int ks = 0; ks < 8; ++ks) {
        const size_t o = (size_t)brow * 2048 + kw + ks * 32 + kfo;
        wbh[ks] = *reinterpret_cast<const bf16x8_t*>(Bh + o);
        wbl[ks] = *reinterpret_cast<const bf16x8_t*>(Bl + o);
      }
    }
    float biasv = 0.f;
    if (tid < 256) {
      const int oo = tid >> 4;
      biasv = (p < 8) ? wbpad[p * 16 + oo] : Wrb[(p - 8) * 16 + oo];
    }

    const size_t axrow = (size_t)(lane & 15) * 2048 + kw + kfo;

    for (int t = 0; t < L_DIM; ++t) {
      // wait for ALL lstm WGs at step t (need full x(t) vector)
      while (true) {
        const int v0 = __hip_atomic_load(&lflags[lane << 4], __ATOMIC_RELAXED,
                                         __HIP_MEMORY_SCOPE_AGENT);
        const int v1 = __hip_atomic_load(&lflags[(64 + lane) << 4], __ATOMIC_RELAXED,
                                         __HIP_MEMORY_SCOPE_AGENT);
        if (__all(v0 > t && v1 > t)) break;
        __builtin_amdgcn_s_sleep(1);
      }

      const size_t xoff = (size_t)t * 32768 + axrow;
      bf16x8_t xh[8], xl[8];
#pragma unroll
      for (int ks = 0; ks < 8; ++ks) {
        xh[ks] = load_bf16x8_sc(XhHi + xoff + ks * 32);
        xl[ks] = load_bf16x8_sc(XhLo + xoff + ks * 32);
      }
      asm volatile("s_waitcnt vmcnt(0)" ::: "memory");
      __builtin_amdgcn_sched_barrier(0);

      f32x4_t acc = {0.f, 0.f, 0.f, 0.f};
#pragma unroll
      for (int ks = 0; ks < 8; ++ks) {
        acc = __builtin_amdgcn_mfma_f32_16x16x32_bf16(xh[ks], wbh[ks], acc, 0, 0, 0);
        acc = __builtin_amdgcn_mfma_f32_16x16x32_bf16(xh[ks], wbl[ks], acc, 0, 0, 0);
        acc = __builtin_amdgcn_mfma_f32_16x16x32_bf16(xl[ks], wbh[ks], acc, 0, 0, 0);
      }
#pragma unroll
      for (int r = 0; r < 4; ++r)
        part[wv][0][(lane >> 4) * 4 + r][lane & 15] = acc[r];
      __syncthreads();

      if (tid < 256) {
        const int bb = tid & 15, oo = tid >> 4;
        float s = 0.f;
#pragma unroll
        for (int v = 0; v < 8; ++v) s += part[v][0][bb][oo];
        s += biasv;
        float* dst;
        if (p < 8) {
          dst = Wall + (size_t)(t * 16 + bb) * 128 + p * 16 + oo;
        } else {
          s = tanhf(s);
          dst = RVall + (size_t)(t * 16 + bb) * 128 + (p - 8) * 16 + oo;
        }
        store_f32_sc(dst, s);
      }
      asm volatile("s_waitcnt vmcnt(0)" ::: "memory");
      __syncthreads();

      if (tid == 0)
        __hip_atomic_store(&pflags[p << 4], t + 1, __ATOMIC_RELAXED,
                           __HIP_MEMORY_SCOPE_AGENT);
    }

  } else {
    // ===================== FWM F-SCAN =====================
    const int b     = wgid - NWGL - NPRJ;
    const int si    = lane >> 1;
    const int rbase = 16 * (lane & 1);
    const int tl    = lane & 31;

    float F[16][4];
#pragma unroll
    for (int i = 0; i < 16; ++i)
#pragma unroll
      for (int j = 0; j < 4; ++j)
        F[i][j] = F0[((size_t)b * 1024 + (16 * lane + i)) * 32 + 4 * wv + j];

    float N = 0.f;
    {
      float loc = 0.f;
#pragma unroll
      for (int i = 0; i < 16; ++i)
#pragma unroll
        for (int j = 0; j < 4; ++j) loc += F[i][j] * F[i][j];
#pragma unroll
      for (int m = 1; m < 64; m <<= 1) loc += __shfl_xor(loc, m);
      if (lane == 0) s_red[wv] = loc;
      __syncthreads();
#pragma unroll
      for (int k = 0; k < 8; ++k) N += s_red[k];
    }

    for (int t = 0; t < 256; ++t) {
      // wait for all 16 proj WGs at step t
      while (true) {
        const int v = __hip_atomic_load(&pflags[(lane & 15) << 4], __ATOMIC_RELAXED,
                                        __HIP_MEMORY_SCOPE_AGENT);
        if (__all(v > t)) break;
        __builtin_amdgcn_s_sleep(1);
      }

      float wpre = 0.f, rvpre = 0.f;
      if (tid < 97)  wpre = load_f32_sc(Wall + (size_t)(t * 16 + b) * 128 + tid);
      if (tid >= 128 && tid < 256)
        rvpre = load_f32_sc(RVall + (size_t)(t * 16 + b) * 128 + tid - 128);
      asm volatile("s_waitcnt vmcnt(0)" ::: "memory");
      __syncthreads();                // A: prior step's s_* readers done
      if (tid < 32)       s_s[tid]       = tanhf(wpre);
      else if (tid < 64)  s_r[tid - 32]  = tanhf(wpre);
      else if (tid < 96)  s_tv[tid - 64] = tanhf(wpre);
      else if (tid == 96) s_bb           = sigmoidf_(wpre + 1.f);
      else if (tid >= 128 && tid < 256) s_rv[tid - 128] = rvpre;
      __syncthreads();                // B

      const float sv = s_s[si];
      float sr[16];
#pragma unroll
      for (int i = 0; i < 16; ++i) sr[i] = sv * s_r[rbase + i];

      float vv4[4];
#pragma unroll
      for (int j = 0; j < 4; ++j) {
        float pp = 0.f;
#pragma unroll
        for (int i = 0; i < 16; ++i) pp += sr[i] * F[i][j];
#pragma unroll
        for (int m = 1; m < 64; m <<= 1) pp += __shfl_xor(pp, m);
        vv4[j] = pp;
      }
      if (lane == 0) {
#pragma unroll
        for (int j = 0; j < 4; ++j) s_v[4 * wv + j] = vv4[j];
      }
      __syncthreads();                // C

      const float vt  = s_v[tl];
      const float ut  = s_bb * (s_tv[tl] - vt);
      const float sl  = s_s[tl];
      const float rl  = s_r[tl];
      float uv = ut * vt, uu = ut * ut, ss = sl * sl, rr = rl * rl;
#pragma unroll
      for (int m = 1; m < 32; m <<= 1) {
        uv += __shfl_xor(uv, m);
        uu += __shfl_xor(uu, m);
        ss += __shfl_xor(ss, m);
        rr += __shfl_xor(rr, m);
      }
      const float Np  = N + 2.f * uv + ss * rr * uu;
      const float n_  = sqrtf(Np);
      const float inv = 1.f / (fmaxf(n_ - 1.f, 0.f) + 1.f);
      N = Np * inv * inv;

      float uw[4];
#pragma unroll
      for (int j = 0; j < 4; ++j) uw[j] = __shfl(ut, 4 * wv + j);
#pragma unroll
      for (int i = 0; i < 16; ++i)
#pragma unroll
        for (int j = 0; j < 4; ++j)
          F[i][j] = (F[i][j] + sr[i] * uw[j]) * inv;

      float* gout = Gbuf + ((size_t)(t * 16 + b) * 3) * 1024;
#pragma unroll
      for (int jit = 0; jit < 3; ++jit) {
        float rjv[16];
#pragma unroll
        for (int i = 0; i < 16; ++i) rjv[i] = s_rv[32 + 32 * jit + rbase + i];
        f32x4_t gv;
#pragma unroll
        for (int j = 0; j < 4; ++j) {
          float g = 0.f;
#pragma unroll
          for (int i = 0; i < 16; ++i) g += rjv[i] * F[i][j];
          g += __shfl_xor(g, 1);
          gv[j] = g;
        }
        if ((lane & 1) == 0)
          *reinterpret_cast<f32x4_t*>(gout + jit * 1024 + (lane >> 1) * 32 + 4 * wv) = gv;
      }
    }
  }
}

// ---------------------------------------------------------------------------
// K4b: FWM q-readout — 4096 independent (t,b) chains, one wave each.
// ---------------------------------------------------------------------------
__global__ __launch_bounds__(256) void fwm_qread(const float* __restrict__ Gbuf,   // (4096,3,32,32)
                                                 const float* __restrict__ RVall,  // (4096,128)
                                                 float* __restrict__ QS)           // (4096,32)
{
  const int pair = blockIdx.x * 4 + (threadIdx.x >> 6);  // t*16+b
  const int lane = threadIdx.x & 63;
  const int tq    = lane & 31;
  const int ihalf = (lane >> 5) * 16;

  const float* G  = Gbuf + (size_t)pair * 3 * 1024;
  float q = RVall[(size_t)pair * 128 + tq];
#pragma unroll 1
  for (int jit = 0; jit < 3; ++jit) {
    float c = 0.f;
#pragma unroll
    for (int i = 0; i < 16; ++i) {
      const float qi = __shfl(q, ihalf + i);
      c += qi * G[jit * 1024 + (ihalf + i) * 32 + tq];
    }
    c += __shfl_xor(c, 32);
    float mval = c;
#pragma unroll
    for (int m = 1; m < 32; m <<= 1) mval += __shfl_xor(mval, m);
    mval *= (1.f / 32.f);
    const float dl = c - mval;
    float var = dl * dl;
#pragma unroll
    for (int m = 1; m < 32; m <<= 1) var += __shfl_xor(var, m);
    var *= (1.f / 32.f);
    q = dl * rsqrtf(var + 1e-5f);
  }
  if (lane < 32) QS[(size_t)pair * 32 + lane] = q;
}

// ---------------------------------------------------------------------------
// K5: out = (XhHi+XhLo) + QS @ Wlin^T + blin
// ---------------------------------------------------------------------------
__global__ __launch_bounds__(256) void out_kernel(const bf16* __restrict__ Xh1Hi,
                                                  const bf16* __restrict__ Xh1Lo,
                                                  const float* __restrict__ QS,
                                                  const float* __restrict__ Wlin,  // (2048,32)
                                                  const float* __restrict__ blin,
                                                  float* __restrict__ out)
{
  __shared__ float qs[32];
  const int row = blockIdx.x;
  if (threadIdx.x < 32) qs[threadIdx.x] = QS[(size_t)row * 32 + threadIdx.x];
  __syncthreads();
  for (int h = threadIdx.x; h < H_DIM; h += 256) {
    const size_t xi = (size_t)row * H_DIM + h;
    float acc = (float)Xh1Hi[xi] + (float)Xh1Lo[xi] + blin[h];
    const float* wr = Wlin + (size_t)h * 32;
#pragma unroll
    for (int t2 = 0; t2 < 32; ++t2) acc += qs[t2] * wr[t2];
    out[xi] = acc;
  }
}

// ---------------------------------------------------------------------------
// Workspace (~225 MB): Whh_f 33.5 | Wih_f 33.5 (XhLo alias) | inp_f 16.8
// (XhHi alias) | Gin2 fp16 67.1 | Xh 16.9 | Wq/Wr hi/lo 2.1 | Wall 2.1 |
// RVall 2.1 | QS 0.5 | Gbuf 50.3 | flags 10KB
// ---------------------------------------------------------------------------
extern "C" void kernel_launch(void* const* d_in, const int* in_sizes, int n_in,
                              void* d_out, int out_size, void* d_ws, size_t ws_size,
                              hipStream_t stream)
{
  (void)in_sizes; (void)n_in; (void)out_size; (void)ws_size;
  const float* inp  = (const float*)d_in[0];
  const float* h0   = (const float*)d_in[1];
  const float* c0   = (const float*)d_in[2];
  const float* F0   = (const float*)d_in[3];
  const float* Wih  = (const float*)d_in[4];
  const float* Whh  = (const float*)d_in[5];
  const float* bih  = (const float*)d_in[6];
  const float* bhh  = (const float*)d_in[7];
  const float* Www  = (const float*)d_in[8];
  const float* Wwb  = (const float*)d_in[9];
  const float* Wrw  = (const float*)d_in[10];
  const float* Wrb  = (const float*)d_in[11];
  const float* Wlin = (const float*)d_in[12];
  const float* blin = (const float*)d_in[13];
  float* out = (float*)d_out;

  char* p = (char*)d_ws;
  auto alloc = [&](size_t bytes) {
    char* r = p;
    p += (bytes + 255) & ~(size_t)255;
    return r;
  };
  _Float16* Whh_f = (_Float16*)alloc(16777216ull * 2);   // 33.5 MB
  _Float16* Wih_f = (_Float16*)alloc(16777216ull * 2);   // 33.5 MB
  _Float16* inp_f = (_Float16*)alloc(8388608ull * 2);    // 16.8 MB
  _Float16* Gin2  = (_Float16*)alloc(33554432ull * 2);   // 67.1 MB fp16
  _Float16* Xh    = (_Float16*)alloc(257ull * 32768 * 2);// 16.9 MB
  bf16*  Wq_hi  = (bf16*)alloc(262144ull * 2);
  bf16*  Wq_lo  = (bf16*)alloc(262144ull * 2);
  bf16*  Wr_hi  = (bf16*)alloc(262144ull * 2);
  bf16*  Wr_lo  = (bf16*)alloc(262144ull * 2);
  float* wbpad  = (float*)alloc(128ull * 4);
  float* Wall   = (float*)alloc(524288ull * 4);          // 2.1 MB
  float* RVall  = (float*)alloc(524288ull * 4);          // 2.1 MB
  float* QS     = (float*)alloc(131072ull * 4);          // 0.5 MB
  float* Gbuf   = (float*)alloc(12582912ull * 4);        // 50.3 MB
  int*   flags  = (int*)alloc((NWGL + NPRJ) * 64);       // lflags + pflags
  int*   lflags = flags;
  int*   pflags = flags + NWGL * 16;
  // aliases (strictly later lifetimes):
  bf16*  XhHi  = (bf16*)inp_f;          // written after Gin GEMM consumed inp_f
  bf16*  XhLo  = (bf16*)Wih_f;          // written after Wih consumed

  prep_kernel<<<2048, 256, 0, stream>>>(Wih, Whh, inp, Www, Wwb, Wrw, h0,
                                        Wih_f, Whh_f, inp_f,
                                        Wq_hi, Wq_lo, Wr_hi, Wr_lo, wbpad, Xh);

  // Phase A: Gin2 = x @ W_ih^T + bias (fp16, LSTM-transposed layout)
  gemm_f16<<<dim3(32, 64), 256, 0, stream>>>(inp_f, Wih_f, bih, bhh, Gin2,
                                             MROWS, G4, 2048);

  // Phase B+C+D1 fused: cooperative pipelined LSTM + proj + F-scan
  hipMemsetAsync(flags, 0, (NWGL + NPRJ) * 64, stream);
  {
    void* kargs[] = {
      (void*)&Whh_f, (void*)&Gin2, (void*)&bih, (void*)&bhh, (void*)&c0,
      (void*)&Wq_hi, (void*)&Wq_lo, (void*)&Wr_hi, (void*)&Wr_lo,
      (void*)&wbpad, (void*)&Wrb, (void*)&F0,
      (void*)&Xh, (void*)&XhHi, (void*)&XhLo,
      (void*)&Wall, (void*)&RVall, (void*)&Gbuf,
      (void*)&lflags, (void*)&pflags
    };
    hipLaunchCooperativeKernel((const void*)fused_rnn,
                               dim3(NWGL + NPRJ + NSCN), dim3(512),
                               kargs, 0, stream);
  }

  // Phase D2: q-readout — 4096 independent chains
  fwm_qread<<<1024, 256, 0, stream>>>(Gbuf, RVall, QS);

  // Phase E: out = x + QS @ Wlin^T + blin
  out_kernel<<<4096, 256, 0, stream>>>(XhHi, XhLo, QS, Wlin, blin, out);
}

// Round 16
// 1873.095 us; speedup vs baseline: 1.9145x; 1.0172x over previous
//
#include <hip/hip_runtime.h>
#include <hip/hip_bf16.h>
#include <cstdint>
#include <cstddef>

// Problem constants: L=256, B=16, I=2048, H=2048, S=R=T=32
#define L_DIM 256
#define B_DIM 16
#define I_DIM 2048
#define H_DIM 2048
#define G4    8192
#define MROWS 4096
#define NWGL  128            // LSTM workgroups (each owns 16 hidden units)
#define NPRJ  16             // projection workgroups
#define NSCN  16             // scan workgroups (one per batch)

typedef __hip_bfloat16 bf16;
typedef __bf16 bf16x8_t __attribute__((ext_vector_type(8)));
typedef _Float16 f16x8_t __attribute__((ext_vector_type(8)));
typedef _Float16 f16x4_t __attribute__((ext_vector_type(4)));
typedef float f32x4_t   __attribute__((ext_vector_type(4)));

__device__ __forceinline__ bf16 f2b(float f) { return __float2bfloat16(f); }

__device__ __forceinline__ void gl_lds16(const void* g, void* l) {
  __builtin_amdgcn_global_load_lds(
      (const __attribute__((address_space(1))) unsigned int*)g,
      (__attribute__((address_space(3))) unsigned int*)l, 16, 0, 0);
}

__device__ __forceinline__ float sigmoidf_(float x) { return 1.f / (1.f + expf(-x)); }

// Coherent (IC-through) access helpers — proven fence-free protocol (r8).
__device__ __forceinline__ f16x8_t load_f16x8_sc(const _Float16* p) {
  f16x8_t r;
  asm volatile("global_load_dwordx4 %0, %1, off sc0 sc1" : "=v"(r) : "v"(p));
  return r;
}
__device__ __forceinline__ bf16x8_t load_bf16x8_sc(const bf16* p) {
  bf16x8_t r;
  asm volatile("global_load_dwordx4 %0, %1, off sc0 sc1" : "=v"(r) : "v"(p));
  return r;
}
__device__ __forceinline__ float load_f32_sc(const float* p) {
  float r;
  asm volatile("global_load_dword %0, %1, off sc0 sc1" : "=v"(r) : "v"(p));
  return r;
}
__device__ __forceinline__ unsigned int load_u16_sc(const _Float16* p) {
  unsigned int r;
  asm volatile("global_load_ushort %0, %1, off sc0 sc1" : "=v"(r) : "v"(p));
  return r;
}
__device__ __forceinline__ void store_short_sc(void* p, unsigned int v) {
  asm volatile("global_store_short %0, %1, off sc0 sc1" :: "v"(p), "v"(v) : "memory");
}
__device__ __forceinline__ void store_f32_sc(void* p, float v) {
  asm volatile("global_store_dword %0, %1, off sc0 sc1" :: "v"(p), "v"(v) : "memory");
}

// ---------------------------------------------------------------------------
// K0: prep — fp16 casts, bf16 hi/lo FWM weights, h0 fp16
// ---------------------------------------------------------------------------
__global__ void prep_kernel(const float* __restrict__ Wih, const float* __restrict__ Whh,
                            const float* __restrict__ inp, const float* __restrict__ Www,
                            const float* __restrict__ Wwb, const float* __restrict__ Wrw,
                            const float* __restrict__ h0,
                            _Float16* __restrict__ Wih_f, _Float16* __restrict__ Whh_f,
                            _Float16* __restrict__ inp_f,
                            bf16* __restrict__ Wq_hi, bf16* __restrict__ Wq_lo,
                            bf16* __restrict__ Wr_hi, bf16* __restrict__ Wr_lo,
                            float* __restrict__ wbpad,
                            _Float16* __restrict__ Xh0)
{
  size_t idx0 = (size_t)blockIdx.x * blockDim.x + threadIdx.x;
  size_t stride = (size_t)gridDim.x * blockDim.x;
  for (size_t i = idx0; i < 16777216ull; i += stride) {
    Wih_f[i] = (_Float16)Wih[i];
    Whh_f[i] = (_Float16)Whh[i];
  }
  for (size_t i = idx0; i < 8388608ull; i += stride) inp_f[i] = (_Float16)inp[i];
  for (size_t i = idx0; i < 262144ull; i += stride) {
    size_t r = i >> 11;
    float q = (r < 97) ? Www[i] : 0.f;
    bf16 qh = f2b(q);
    Wq_hi[i] = qh;
    Wq_lo[i] = f2b(q - (float)qh);
    float rr = Wrw[i];
    bf16 rh = f2b(rr);
    Wr_hi[i] = rh;
    Wr_lo[i] = f2b(rr - (float)rh);
  }
  for (size_t i = idx0; i < 128ull; i += stride) wbpad[i] = (i < 97) ? Wwb[i] : 0.f;
  for (size_t i = idx0; i < 32768ull; i += stride) Xh0[i] = (_Float16)h0[i];
}

// ---------------------------------------------------------------------------
// K1: fp16 NT GEMM  C = A * B^T + bias -> fp16 Gin2[t][wg][gate][jj][bb].
// ROUND 16: coalesced epilogue — each lane packs its 4 contiguous bb rows
// (fixed jj column) into one f16x4 8B store; a wave's 64 stores form one
// contiguous 512B segment of Gin2 (replaces 16 scattered 2B stores/thread).
// ---------------------------------------------------------------------------
__global__ __launch_bounds__(256) void gemm_f16(const _Float16* __restrict__ A,
                                                const _Float16* __restrict__ B,
                                                const float* __restrict__ bih,
                                                const float* __restrict__ bhh,
                                                _Float16* __restrict__ Gin2,
                                                int M, int N, int K)
{
  __shared__ __align__(16) _Float16 As[128 * 32];
  __shared__ __align__(16) _Float16 Bs[128 * 32];
  const int tid  = threadIdx.x;
  const int lane = tid & 63;
  const int w    = tid >> 6;
  const int wm   = w >> 1, wn = w & 1;
  const int m0   = blockIdx.x * 128, n0 = blockIdx.y * 128;

  f32x4_t acc[4][4];
#pragma unroll
  for (int m = 0; m < 4; ++m)
#pragma unroll
    for (int n = 0; n < 4; ++n) acc[m][n] = (f32x4_t){0.f, 0.f, 0.f, 0.f};

  for (int k0 = 0; k0 < K; k0 += 32) {
#pragma unroll
    for (int r = 0; r < 2; ++r) {
      const int base = w * 2048 + r * 1024;
      const int off  = base + lane * 16;
      const int e    = off >> 1;
      const int row  = e >> 5;
      const int col  = e & 31;
      gl_lds16(A + (size_t)(m0 + row) * K + (k0 + col), (char*)As + base);
      gl_lds16(B + (size_t)(n0 + row) * K + (k0 + col), (char*)Bs + base);
    }
    __syncthreads();

    f16x8_t af[4], bfr[4];
    const int kb = (lane >> 4) * 16;
#pragma unroll
    for (int m = 0; m < 4; ++m)
      af[m] = *reinterpret_cast<const f16x8_t*>((const char*)As + (wm * 64 + m * 16 + (lane & 15)) * 64 + kb);
#pragma unroll
    for (int n = 0; n < 4; ++n)
      bfr[n] = *reinterpret_cast<const f16x8_t*>((const char*)Bs + (wn * 64 + n * 16 + (lane & 15)) * 64 + kb);
#pragma unroll
    for (int m = 0; m < 4; ++m)
#pragma unroll
      for (int n = 0; n < 4; ++n)
        acc[m][n] = __builtin_amdgcn_mfma_f32_16x16x32_f16(af[m], bfr[n], acc[m][n], 0, 0, 0);
    __syncthreads();
  }

  // Coalesced epilogue: fragment row-block is one t (16 rows), col-block is
  // one (gate, wg) pair (16 cols). bb = (lane>>4)*4+r contiguous per lane.
  const int jj = lane & 15;
#pragma unroll
  for (int n = 0; n < 4; ++n) {
    const int colb = n0 + wn * 64 + n * 16;     // multiple of 16
    const int gate = colb >> 11;
    const int wg   = (colb & 2047) >> 4;
    const float bv = bih[colb + jj] + bhh[colb + jj];
#pragma unroll
    for (int m = 0; m < 4; ++m) {
      const int rowb = m0 + wm * 64 + m * 16;   // multiple of 16
      const int t = rowb >> 4;
      f16x4_t v4;
#pragma unroll
      for (int r = 0; r < 4; ++r) v4[r] = (_Float16)(acc[m][n][r] + bv);
      *reinterpret_cast<f16x4_t*>(
          Gin2 + (((size_t)t * NWGL + wg) * 4 + gate) * 256 + jj * 16 + (lane >> 4) * 4) = v4;
    }
  }
}

// ---------------------------------------------------------------------------
// K2: FUSED persistent RNN (160 WGs x 512 thr, cooperative) — byte-identical
// to round 14 (proven green):
//   WG 0..127   : LSTM (per-wave producer waits)
//   WG 128..143 : projection (polls lstm flags)
//   WG 144..159 : FWM F-scan (polls proj flags), G (fp16) -> global
// ---------------------------------------------------------------------------
__global__ __launch_bounds__(512, 2) void fused_rnn(
    const _Float16* __restrict__ Whh,
    const _Float16* __restrict__ Gin2,   // (256,128,4,16,16) fp16
    const float* __restrict__ bih, const float* __restrict__ bhh,
    const float* __restrict__ c0,
    const bf16* __restrict__ Wq_hi, const bf16* __restrict__ Wq_lo,
    const bf16* __restrict__ Wr_hi, const bf16* __restrict__ Wr_lo,
    const float* __restrict__ wbpad, const float* __restrict__ Wrb,
    const float* __restrict__ F0,
    _Float16* __restrict__ Xh,
    bf16* __restrict__ XhHi, bf16* __restrict__ XhLo,
    float* __restrict__ Wall, float* __restrict__ RVall,
    _Float16* __restrict__ Gbuf,
    int* lflags, int* pflags)
{
  __shared__ float part[8][4][16][17];          // lstm reduce; proj uses [][0]
  __shared__ float s_s[32], s_r[32], s_tv[32], s_bb;
  __shared__ float s_rv[128];
  __shared__ float s_v[32];
  __shared__ float s_red[8];

  const int wgid = blockIdx.x;
  const int tid  = threadIdx.x;
  const int lane = tid & 63;
  const int wv   = tid >> 6;          // 0..7

  if (wgid < NWGL) {
    // ===================== LSTM =====================
    const int wg = wgid;
    const int j0 = wg * 16;
    const int kw = wv * 256;

    f16x8_t whh[4][8];
    {
      const int nn  = lane & 15;
      const int kfo = (lane >> 4) * 8;
#pragma unroll
      for (int g = 0; g < 4; ++g) {
        const size_t grow = (size_t)(g * H_DIM + j0 + nn) * 2048;
#pragma unroll
        for (int ks = 0; ks < 8; ++ks)
          whh[g][ks] = *reinterpret_cast<const f16x8_t*>(Whh + grow + kw + ks * 32 + kfo);
      }
    }

    float c_reg = 0.f, cbr0 = 0.f, cbr1 = 0.f, cbr2 = 0.f, cbr3 = 0.f;
    if (tid < 256) {
      const int bb = tid & 15, jj = tid >> 4;
      const int j = j0 + jj;
      c_reg = c0[bb * H_DIM + j];
      cbr0 = bih[0 * H_DIM + j] + bhh[0 * H_DIM + j];
      cbr1 = bih[1 * H_DIM + j] + bhh[1 * H_DIM + j];
      cbr2 = bih[2 * H_DIM + j] + bhh[2 * H_DIM + j];
      cbr3 = bih[3 * H_DIM + j] + bhh[3 * H_DIM + j];
    }

    const size_t arow = (size_t)(lane & 15) * 2048 + kw + (lane >> 4) * 8;
    const int fidx = ((wv << 4) + (lane & 15)) << 4;   // this wave's producers

    for (int t = 0; t < L_DIM; ++t) {
      if (t > 0) {
        while (true) {
          const int v = __hip_atomic_load(&lflags[fidx], __ATOMIC_RELAXED,
                                          __HIP_MEMORY_SCOPE_AGENT);
          if (__all(v >= t)) break;
          __builtin_amdgcn_s_sleep(1);
        }
      }

      float gin0 = 0.f, gin1 = 0.f, gin2v = 0.f, gin3 = 0.f;
      if (tid < 256) {
        const _Float16* gbase = Gin2 + ((size_t)t * NWGL + wg) * 1024;
        gin0  = (float)gbase[0 * 256 + tid];
        gin1  = (float)gbase[1 * 256 + tid];
        gin2v = (float)gbase[2 * 256 + tid];
        gin3  = (float)gbase[3 * 256 + tid];
      }

      const size_t hoff = (size_t)t * 32768 + arow;
      f16x8_t hf[8];
#pragma unroll
      for (int ks = 0; ks < 8; ++ks)
        hf[ks] = load_f16x8_sc(Xh + hoff + ks * 32);
      asm volatile("s_waitcnt vmcnt(0)" ::: "memory");
      __builtin_amdgcn_sched_barrier(0);

      f32x4_t acc[4];
#pragma unroll
      for (int g = 0; g < 4; ++g) acc[g] = (f32x4_t){0.f, 0.f, 0.f, 0.f};
#pragma unroll
      for (int ks = 0; ks < 8; ++ks) {
#pragma unroll
        for (int g = 0; g < 4; ++g)
          acc[g] = __builtin_amdgcn_mfma_f32_16x16x32_f16(hf[ks], whh[g][ks], acc[g], 0, 0, 0);
      }
#pragma unroll
      for (int g = 0; g < 4; ++g)
#pragma unroll
        for (int r = 0; r < 4; ++r)
          part[wv][g][(lane >> 4) * 4 + r][lane & 15] = acc[g][r];
      __syncthreads();

      if (tid < 256) {
        const int bb = tid & 15, jj = tid >> 4;
        float g4[4] = {gin0, gin1, gin2v, gin3};
        const float cb4[4] = {cbr0, cbr1, cbr2, cbr3};
#pragma unroll
        for (int g = 0; g < 4; ++g) {
          float s = 0.f;
#pragma unroll
          for (int v = 0; v < 8; ++v) s += part[v][g][bb][jj];
          g4[g] += s + cb4[g];
        }
        const float i_ = sigmoidf_(g4[0]);
        const float f_ = sigmoidf_(g4[1]);
        const float g_ = tanhf(g4[2]);
        const float o_ = sigmoidf_(g4[3]);
        c_reg = f_ * c_reg + i_ * g_;
        const float h = o_ * tanhf(c_reg);
        const int bj = bb * 2048 + j0 + jj;
        const _Float16 hF = (_Float16)h;
        const bf16 hhv = f2b(h);
        const bf16 hlv = f2b(h - (float)hhv);
        const size_t xi = ((size_t)t * 16 + bb) * 2048 + j0 + jj;
        store_short_sc(Xh + (size_t)(t + 1) * 32768 + bj,
                       (unsigned int)__builtin_bit_cast(unsigned short, hF));
        store_short_sc(XhHi + xi,
                       (unsigned int)__builtin_bit_cast(unsigned short, hhv));
        store_short_sc(XhLo + xi,
                       (unsigned int)__builtin_bit_cast(unsigned short, hlv));
      }
      asm volatile("s_waitcnt vmcnt(0)" ::: "memory");
      __syncthreads();

      if (tid == 0)
        __hip_atomic_store(&lflags[wg << 4], t + 1, __ATOMIC_RELAXED,
                           __HIP_MEMORY_SCOPE_AGENT);
    }

  } else if (wgid < NWGL + NPRJ) {
    // ===================== PROJECTION =====================
    const int p   = wgid - NWGL;     // 0..15 ; cols [16p,16p+16) of [Wq;Wr]
    const int kw  = wv * 256;
    const int nn  = lane & 15;
    const int kfo = (lane >> 4) * 8;

    bf16x8_t wbh[8], wbl[8];
    {
      const bf16* Bh = (p < 8) ? Wq_hi : Wr_hi;
      const bf16* Bl = (p < 8) ? Wq_lo : Wr_lo;
      const int brow = (p < 8) ? (p * 16 + nn) : ((p - 8) * 16 + nn);
#pragma unroll
      for (int ks = 0; ks < 8; ++ks) {
        const size_t o = (size_t)brow * 2048 + kw + ks * 32 + kfo;
        wbh[ks] = *reinterpret_cast<const bf16x8_t*>(Bh + o);
        wbl[ks] = *reinterpret_cast<const bf16x8_t*>(Bl + o);
      }
    }
    float biasv = 0.f;
    if (tid < 256) {
      const int oo = tid >> 4;
      biasv = (p < 8) ? wbpad[p * 16 + oo] : Wrb[(p - 8) * 16 + oo];
    }

    const size_t axrow = (size_t)(lane & 15) * 2048 + kw + kfo;

    for (int t = 0; t < L_DIM; ++t) {
      while (true) {
        const int v0 = __hip_atomic_load(&lflags[lane << 4], __ATOMIC_RELAXED,
                                         __HIP_MEMORY_SCOPE_AGENT);
        const int v1 = __hip_atomic_load(&lflags[(64 + lane) << 4], __ATOMIC_RELAXED,
                                         __HIP_MEMORY_SCOPE_AGENT);
        if (__all(v0 > t && v1 > t)) break;
        __builtin_amdgcn_s_sleep(1);
      }

      const size_t xoff = (size_t)t * 32768 + axrow;
      bf16x8_t xh[8], xl[8];
#pragma unroll
      for (int ks = 0; ks < 8; ++ks) {
        xh[ks] = load_bf16x8_sc(XhHi + xoff + ks * 32);
        xl[ks] = load_bf16x8_sc(XhLo + xoff + ks * 32);
      }
      asm volatile("s_waitcnt vmcnt(0)" ::: "memory");
      __builtin_amdgcn_sched_barrier(0);

      f32x4_t acc = {0.f, 0.f, 0.f, 0.f};
#pragma unroll
      for (int ks = 0; ks < 8; ++ks) {
        acc = __builtin_amdgcn_mfma_f32_16x16x32_bf16(xh[ks], wbh[ks], acc, 0, 0, 0);
        acc = __builtin_amdgcn_mfma_f32_16x16x32_bf16(xh[ks], wbl[ks], acc, 0, 0, 0);
        acc = __builtin_amdgcn_mfma_f32_16x16x32_bf16(xl[ks], wbh[ks], acc, 0, 0, 0);
      }
#pragma unroll
      for (int r = 0; r < 4; ++r)
        part[wv][0][(lane >> 4) * 4 + r][lane & 15] = acc[r];
      __syncthreads();

      if (tid < 256) {
        const int bb = tid & 15, oo = tid >> 4;
        float s = 0.f;
#pragma unroll
        for (int v = 0; v < 8; ++v) s += part[v][0][bb][oo];
        s += biasv;
        float* dst;
        if (p < 8) {
          dst = Wall + (size_t)(t * 16 + bb) * 128 + p * 16 + oo;
        } else {
          s = tanhf(s);
          dst = RVall + (size_t)(t * 16 + bb) * 128 + (p - 8) * 16 + oo;
        }
        store_f32_sc(dst, s);
      }
      asm volatile("s_waitcnt vmcnt(0)" ::: "memory");
      __syncthreads();

      if (tid == 0)
        __hip_atomic_store(&pflags[p << 4], t + 1, __ATOMIC_RELAXED,
                           __HIP_MEMORY_SCOPE_AGENT);
    }

  } else {
    // ===================== FWM F-SCAN =====================
    const int b     = wgid - NWGL - NPRJ;
    const int si    = lane >> 1;
    const int rbase = 16 * (lane & 1);
    const int tl    = lane & 31;

    float F[16][4];
#pragma unroll
    for (int i = 0; i < 16; ++i)
#pragma unroll
      for (int j = 0; j < 4; ++j)
        F[i][j] = F0[((size_t)b * 1024 + (16 * lane + i)) * 32 + 4 * wv + j];

    float N = 0.f;
    {
      float loc = 0.f;
#pragma unroll
      for (int i = 0; i < 16; ++i)
#pragma unroll
        for (int j = 0; j < 4; ++j) loc += F[i][j] * F[i][j];
#pragma unroll
      for (int m = 1; m < 64; m <<= 1) loc += __shfl_xor(loc, m);
      if (lane == 0) s_red[wv] = loc;
      __syncthreads();
#pragma unroll
      for (int k = 0; k < 8; ++k) N += s_red[k];
    }

    for (int t = 0; t < 256; ++t) {
      while (true) {
        const int v = __hip_atomic_load(&pflags[(lane & 15) << 4], __ATOMIC_RELAXED,
                                        __HIP_MEMORY_SCOPE_AGENT);
        if (__all(v > t)) break;
        __builtin_amdgcn_s_sleep(1);
      }

      float wpre = 0.f, rvpre = 0.f;
      if (tid < 97)  wpre = load_f32_sc(Wall + (size_t)(t * 16 + b) * 128 + tid);
      if (tid >= 128 && tid < 256)
        rvpre = load_f32_sc(RVall + (size_t)(t * 16 + b) * 128 + tid - 128);
      asm volatile("s_waitcnt vmcnt(0)" ::: "memory");
      __syncthreads();                // A
      if (tid < 32)       s_s[tid]       = tanhf(wpre);
      else if (tid < 64)  s_r[tid - 32]  = tanhf(wpre);
      else if (tid < 96)  s_tv[tid - 64] = tanhf(wpre);
      else if (tid == 96) s_bb           = sigmoidf_(wpre + 1.f);
      else if (tid >= 128 && tid < 256) s_rv[tid - 128] = rvpre;
      __syncthreads();                // B

      const float sv = s_s[si];
      float sr[16];
#pragma unroll
      for (int i = 0; i < 16; ++i) sr[i] = sv * s_r[rbase + i];

      float vv4[4];
#pragma unroll
      for (int j = 0; j < 4; ++j) {
        float pp = 0.f;
#pragma unroll
        for (int i = 0; i < 16; ++i) pp += sr[i] * F[i][j];
#pragma unroll
        for (int m = 1; m < 64; m <<= 1) pp += __shfl_xor(pp, m);
        vv4[j] = pp;
      }
      if (lane == 0) {
#pragma unroll
        for (int j = 0; j < 4; ++j) s_v[4 * wv + j] = vv4[j];
      }
      __syncthreads();                // C

      const float vt  = s_v[tl];
      const float ut  = s_bb * (s_tv[tl] - vt);
      const float sl  = s_s[tl];
      const float rl  = s_r[tl];
      float uv = ut * vt, uu = ut * ut, ss = sl * sl, rr = rl * rl;
#pragma unroll
      for (int m = 1; m < 32; m <<= 1) {
        uv += __shfl_xor(uv, m);
        uu += __shfl_xor(uu, m);
        ss += __shfl_xor(ss, m);
        rr += __shfl_xor(rr, m);
      }
      const float Np  = N + 2.f * uv + ss * rr * uu;
      const float n_  = sqrtf(Np);
      const float inv = 1.f / (fmaxf(n_ - 1.f, 0.f) + 1.f);
      N = Np * inv * inv;

      float uw[4];
#pragma unroll
      for (int j = 0; j < 4; ++j) uw[j] = __shfl(ut, 4 * wv + j);
#pragma unroll
      for (int i = 0; i < 16; ++i)
#pragma unroll
        for (int j = 0; j < 4; ++j)
          F[i][j] = (F[i][j] + sr[i] * uw[j]) * inv;

      _Float16* gout = Gbuf + ((size_t)(t * 16 + b) * 3) * 1024;
#pragma unroll
      for (int jit = 0; jit < 3; ++jit) {
        float rjv[16];
#pragma unroll
        for (int i = 0; i < 16; ++i) rjv[i] = s_rv[32 + 32 * jit + rbase + i];
        f16x4_t gv;
#pragma unroll
        for (int j = 0; j < 4; ++j) {
          float g = 0.f;
#pragma unroll
          for (int i = 0; i < 16; ++i) g += rjv[i] * F[i][j];
          g += __shfl_xor(g, 1);
          gv[j] = (_Float16)g;
        }
        if ((lane & 1) == 0)
          *reinterpret_cast<f16x4_t*>(gout + jit * 1024 + (lane >> 1) * 32 + 4 * wv) = gv;
      }
    }
  }
}

// ---------------------------------------------------------------------------
// K3: fused q-readout + output. One block per row (t*16+b): wave 0 runs the
// 3x(q.G + LN) chain into LDS, then all threads emit the output row.
// ---------------------------------------------------------------------------
__global__ __launch_bounds__(256) void qread_out(const _Float16* __restrict__ Gbuf,  // (4096,3,32,32) f16
                                                 const float* __restrict__ RVall,    // (4096,128)
                                                 const bf16* __restrict__ Xh1Hi,
                                                 const bf16* __restrict__ Xh1Lo,
                                                 const float* __restrict__ Wlin,     // (2048,32)
                                                 const float* __restrict__ blin,
                                                 float* __restrict__ out)
{
  __shared__ float qs[32];
  const int row = blockIdx.x;          // t*16+b
  const int tid = threadIdx.x;

  if (tid < 64) {
    const int lane  = tid;
    const int tq    = lane & 31;
    const int ihalf = (lane >> 5) * 16;
    const _Float16* G = Gbuf + (size_t)row * 3 * 1024;
    float q = RVall[(size_t)row * 128 + tq];
#pragma unroll 1
    for (int jit = 0; jit < 3; ++jit) {
      float c = 0.f;
#pragma unroll
      for (int i = 0; i < 16; ++i) {
        const float qi = __shfl(q, ihalf + i);
        c += qi * (float)G[jit * 1024 + (ihalf + i) * 32 + tq];
      }
      c += __shfl_xor(c, 32);
      float mval = c;
#pragma unroll
      for (int m = 1; m < 32; m <<= 1) mval += __shfl_xor(mval, m);
      mval *= (1.f / 32.f);
      const float dl = c - mval;
      float var = dl * dl;
#pragma unroll
      for (int m = 1; m < 32; m <<= 1) var += __shfl_xor(var, m);
      var *= (1.f / 32.f);
      q = dl * rsqrtf(var + 1e-5f);
    }
    if (lane < 32) qs[lane] = q;
  }
  __syncthreads();

  for (int h = tid; h < H_DIM; h += 256) {
    const size_t xi = (size_t)row * H_DIM + h;
    float acc = (float)Xh1Hi[xi] + (float)Xh1Lo[xi] + blin[h];
    const float* wr = Wlin + (size_t)h * 32;
#pragma unroll
    for (int t2 = 0; t2 < 32; ++t2) acc += qs[t2] * wr[t2];
    out[xi] = acc;
  }
}

// ---------------------------------------------------------------------------
// Workspace (~216 MB): Whh_f 33.5 | Wih_f 33.5 | inp_f 16.8 (XhHi alias —
// safe: gemm_f16 fully consumes inp_f before fused launches) | Gin2 fp16
// 67.1 | Xh 16.9 | XhLo 16.8 | Wq/Wr 2.1 | Wall/RVall 4.2 | Gbuf fp16 25.2 |
// flags 10KB
// ---------------------------------------------------------------------------
extern "C" void kernel_launch(void* const* d_in, const int* in_sizes, int n_in,
                              void* d_out, int out_size, void* d_ws, size_t ws_size,
                              hipStream_t stream)
{
  (void)in_sizes; (void)n_in; (void)out_size; (void)ws_size;
  const float* inp  = (const float*)d_in[0];
  const float* h0   = (const float*)d_in[1];
  const float* c0   = (const float*)d_in[2];
  const float* F0   = (const float*)d_in[3];
  const float* Wih  = (const float*)d_in[4];
  const float* Whh  = (const float*)d_in[5];
  const float* bih  = (const float*)d_in[6];
  const float* bhh  = (const float*)d_in[7];
  const float* Www  = (const float*)d_in[8];
  const float* Wwb  = (const float*)d_in[9];
  const float* Wrw  = (const float*)d_in[10];
  const float* Wrb  = (const float*)d_in[11];
  const float* Wlin = (const float*)d_in[12];
  const float* blin = (const float*)d_in[13];
  float* out = (float*)d_out;

  char* p = (char*)d_ws;
  auto alloc = [&](size_t bytes) {
    char* r = p;
    p += (bytes + 255) & ~(size_t)255;
    return r;
  };
  _Float16* Whh_f = (_Float16*)alloc(16777216ull * 2);   // 33.5 MB
  _Float16* Wih_f = (_Float16*)alloc(16777216ull * 2);   // 33.5 MB
  _Float16* inp_f = (_Float16*)alloc(8388608ull * 2);    // 16.8 MB
  _Float16* Gin2  = (_Float16*)alloc(33554432ull * 2);   // 67.1 MB fp16
  _Float16* Xh    = (_Float16*)alloc(257ull * 32768 * 2);// 16.9 MB
  bf16*     XhLo  = (bf16*)alloc(8388608ull * 2);        // 16.8 MB dedicated
  bf16*  Wq_hi  = (bf16*)alloc(262144ull * 2);
  bf16*  Wq_lo  = (bf16*)alloc(262144ull * 2);
  bf16*  Wr_hi  = (bf16*)alloc(262144ull * 2);
  bf16*  Wr_lo  = (bf16*)alloc(262144ull * 2);
  float* wbpad  = (float*)alloc(128ull * 4);
  float* Wall   = (float*)alloc(524288ull * 4);          // 2.1 MB
  float* RVall  = (float*)alloc(524288ull * 4);          // 2.1 MB
  _Float16* Gbuf = (_Float16*)alloc(12582912ull * 2);    // 25.2 MB fp16
  int*   flags  = (int*)alloc((NWGL + NPRJ) * 64);       // lflags + pflags
  int*   lflags = flags;
  int*   pflags = flags + NWGL * 16;
  // alias (safe: gemm_f16 consumes all of inp_f before fused_rnn launches):
  bf16*  XhHi  = (bf16*)inp_f;

  prep_kernel<<<2048, 256, 0, stream>>>(Wih, Whh, inp, Www, Wwb, Wrw, h0,
                                        Wih_f, Whh_f, inp_f,
                                        Wq_hi, Wq_lo, Wr_hi, Wr_lo, wbpad, Xh);

  // Phase A: Gin2 = x @ W_ih^T + bias (fp16, coalesced transposed epilogue)
  gemm_f16<<<dim3(32, 64), 256, 0, stream>>>(inp_f, Wih_f, bih, bhh, Gin2,
                                             MROWS, G4, 2048);

  // Phase B+C+D1 fused: cooperative pipelined LSTM + proj + F-scan
  hipMemsetAsync(flags, 0, (NWGL + NPRJ) * 64, stream);
  {
    void* kargs[] = {
      (void*)&Whh_f, (void*)&Gin2, (void*)&bih, (void*)&bhh, (void*)&c0,
      (void*)&Wq_hi, (void*)&Wq_lo, (void*)&Wr_hi, (void*)&Wr_lo,
      (void*)&wbpad, (void*)&Wrb, (void*)&F0,
      (void*)&Xh, (void*)&XhHi, (void*)&XhLo,
      (void*)&Wall, (void*)&RVall, (void*)&Gbuf,
      (void*)&lflags, (void*)&pflags
    };
    hipLaunchCooperativeKernel((const void*)fused_rnn,
                               dim3(NWGL + NPRJ + NSCN), dim3(512),
                               kargs, 0, stream);
  }

  // Phase D2+E fused: q-readout + output
  qread_out<<<4096, 256, 0, stream>>>(Gbuf, RVall, XhHi, XhLo, Wlin, blin, out);
}